// Round 1
// baseline (23617.415 us; speedup 1.0000x reference)
//
#include <hip/hip_runtime.h>
#include <cmath>

#define NN 100000
#define EE 1600000
#define H 128
#define PP 16
#define NB 8
#define NT 32

__device__ __forceinline__ float dot4(float4 a, float4 b){
  return a.x*b.x + a.y*b.y + a.z*b.z + a.w*b.w;
}
__device__ __forceinline__ float wred64(float v){
  v += __shfl_xor(v,32); v += __shfl_xor(v,16); v += __shfl_xor(v,8);
  v += __shfl_xor(v,4);  v += __shfl_xor(v,2);  v += __shfl_xor(v,1);
  return v;
}
// 2x 128-thread-group (sum,sumsq) reduce. ALL 256 threads must call in lockstep.
__device__ __forceinline__ void grpred2(float a, float b, float& oa, float& ob, float* r, int tid){
  float sa=wred64(a), sb=wred64(b);
  int w=tid>>6;
  __syncthreads();
  if ((tid&63)==0){ r[w*2]=sa; r[w*2+1]=sb; }
  __syncthreads();
  int g2=(tid>>7)*2;
  oa=r[g2*2]+r[g2*2+2];
  ob=r[g2*2+1]+r[g2*2+3];
}

// ---- edge_index dtype detect: flag=1 if int64 (odd words all zero), else 0
__global__ void detect_kernel(const int* __restrict__ ei, int* __restrict__ flag){
  __shared__ int nz;
  if (threadIdx.x==0) nz=0;
  __syncthreads();
  for (int i=threadIdx.x; i<2048; i+=256){
    if (ei[2*i+1]!=0) nz=1;
  }
  __syncthreads();
  if (threadIdx.x==0) flag[0] = nz ? 0 : 1;
}

// ---- encoder: tokens[n,0,:] = LN(x @ enc_w^T + enc_b)
__global__ __launch_bounds__(256) void enc_kernel(
    const float* __restrict__ x, const float* __restrict__ w, const float* __restrict__ b,
    const float* __restrict__ g, const float* __restrict__ bb, float* __restrict__ tokens){
  __shared__ __align__(16) float xs[2][H];
  __shared__ float r[8];
  int tid=threadIdx.x, h=tid&127, tg=tid>>7;
  int n=blockIdx.x*2+tg;
  xs[tg][h]=x[(size_t)n*H+h];
  __syncthreads();
  float acc=b[h];
  const float4* wr=(const float4*)(w+(size_t)h*H);
  const float4* xv=(const float4*)xs[tg];
  #pragma unroll 4
  for (int d4=0; d4<32; d4++) acc += dot4(wr[d4], xv[d4]);
  float s,ss; grpred2(acc, acc*acc, s, ss, r, tid);
  float m=s*(1.f/H), var=ss*(1.f/H)-m*m;
  tokens[(size_t)n*4*H+h] = (acc-m)*rsqrtf(var+1e-5f)*g[h]+bb[h];
}

// ---- histograms: deg over col (float), counts over row (int)
__global__ void hist_kernel(const int* __restrict__ ei, const int* __restrict__ flag,
                            float* __restrict__ deg, int* __restrict__ counts){
  int f=flag[0];
  int e=blockIdx.x*256+threadIdx.x;
  if (e>=EE) return;
  int rw=ei[(size_t)e<<f];
  int cl=ei[((size_t)EE+e)<<f];
  atomicAdd(&counts[rw],1);
  atomicAdd(&deg[cl],1.0f);
}

__global__ void dinv_kernel(float* __restrict__ deg){
  int i=blockIdx.x*256+threadIdx.x;
  if (i<NN) deg[i]=rsqrtf(fmaxf(deg[i],1.0f));
}

// ---- single-block exclusive scan of counts -> row_ptr, cursor
__global__ __launch_bounds__(1024) void scan_kernel(const int* __restrict__ counts,
                                                    int* __restrict__ row_ptr, int* __restrict__ cursor){
  __shared__ int wsum_s[16];
  __shared__ int carry_s;
  int tid=threadIdx.x, lane=tid&63, w=tid>>6;
  if (tid==0) carry_s=0;
  __syncthreads();
  for (int base=0; base<NN; base+=1024){
    int i=base+tid;
    int v=(i<NN)?counts[i]:0;
    int x=v;
    for (int off=1; off<64; off<<=1){
      int t=__shfl_up(x,off);
      if (lane>=off) x+=t;
    }
    if (lane==63) wsum_s[w]=x;
    __syncthreads();
    int woff=0;
    #pragma unroll
    for (int ww=0; ww<16; ww++) if (ww<w) woff+=wsum_s[ww];
    int carry=carry_s;
    int excl=carry+woff+x-v;
    if (i<NN){ row_ptr[i]=excl; cursor[i]=excl; }
    __syncthreads();
    if (tid==1023) carry_s = carry + woff + x;
    __syncthreads();
  }
  if (tid==0) row_ptr[NN]=carry_s;
}

// ---- scatter edges into CSR (col + weight)
__global__ void scatter_kernel(const int* __restrict__ ei, const int* __restrict__ flag,
                               int* __restrict__ cursor, const float* __restrict__ dinv,
                               int* __restrict__ cs_col, float* __restrict__ cs_w){
  int f=flag[0];
  int e=blockIdx.x*256+threadIdx.x;
  if (e>=EE) return;
  int rw=ei[(size_t)e<<f];
  int cl=ei[((size_t)EE+e)<<f];
  int pos=atomicAdd(&cursor[rw],1);
  cs_col[pos]=cl;
  cs_w[pos]=dinv[rw]*dinv[cl];
}

// ---- SpMM hop: tokens[:,k+1,:] = A_norm @ tokens[:,k,:]
__global__ __launch_bounds__(256) void spmm_kernel(float* __restrict__ tokens,
    const int* __restrict__ row_ptr, const int* __restrict__ cs_col,
    const float* __restrict__ cs_w, int k){
  int tid=threadIdx.x;
  int n=blockIdx.x*2+(tid>>7);
  int t=tid&127;
  int beg=row_ptr[n], end=row_ptr[n+1];
  float acc=0.f;
  const float* src=tokens+(size_t)k*H+t;
  for (int j=beg;j<end;j++){
    acc += cs_w[j]*src[(size_t)cs_col[j]*(4*H)];
  }
  tokens[((size_t)n*4+k+1)*H+t]=acc;
}

// ---- PE: tokens[n,0,:] += rho(sum_p relu(phi))
__global__ __launch_bounds__(256) void pe_kernel(
    const float* __restrict__ eigvecs, const float* __restrict__ eigvals,
    const float* __restrict__ phi_w1, const float* __restrict__ phi_w2,
    const float* __restrict__ rho_w1, const float* __restrict__ rho_b1,
    const float* __restrict__ rho_w2, const float* __restrict__ rho_b2,
    const float* __restrict__ pe_eps, float* __restrict__ tokens){
  __shared__ __align__(16) float fe[2][PP][2];
  __shared__ __align__(16) float sb[2][H];
  int tid=threadIdx.x, h=tid&127, tg=tid>>7;
  int n=blockIdx.x*2+tg;
  if (h<PP){
    float a=eigvecs[(size_t)n*PP+h];
    float b=eigvals[(size_t)n*PP+h]+pe_eps[h];
    fe[tg][h][0]=isnan(a)?0.f:a;
    fe[tg][h][1]=isnan(b)?0.f:b;
  }
  __syncthreads();
  float wa=phi_w1[h*2], wb=phi_w1[h*2+1];
  float sp=0.f;
  #pragma unroll
  for (int p=0;p<PP;p++){
    float fv=fe[tg][p][0]*wa+fe[tg][p][1]*wb;
    sp += fmaxf(fv,0.f);
  }
  sb[tg][h]=sp;
  __syncthreads();
  float s=0.f;
  { const float4* wr=(const float4*)(phi_w2+(size_t)h*H);
    const float4* xv=(const float4*)sb[tg];
    #pragma unroll 4
    for (int d4=0;d4<32;d4++) s+=dot4(wr[d4],xv[d4]); }
  __syncthreads();
  sb[tg][h]=s;
  __syncthreads();
  float t1=rho_b1[h];
  { const float4* wr=(const float4*)(rho_w1+(size_t)h*H);
    const float4* xv=(const float4*)sb[tg];
    #pragma unroll 4
    for (int d4=0;d4<32;d4++) t1+=dot4(wr[d4],xv[d4]); }
  t1=fmaxf(t1,0.f);
  __syncthreads();
  sb[tg][h]=t1;
  __syncthreads();
  float pe=rho_b2[h];
  { const float4* wr=(const float4*)(rho_w2+(size_t)h*H);
    const float4* xv=(const float4*)sb[tg];
    #pragma unroll 4
    for (int d4=0;d4<32;d4++) pe+=dot4(wr[d4],xv[d4]); }
  tokens[(size_t)n*4*H+h] += pe;
}

// ---- fused 2-layer transformer + head for NB nodes / block
__global__ __launch_bounds__(256,1) void xform_kernel(
    const float* __restrict__ tokens, const float* __restrict__ hop_emb,
    const float* __restrict__ qkv_w, const float* __restrict__ qkv_b,
    const float* __restrict__ out_w, const float* __restrict__ out_b,
    const float* __restrict__ ln1_g, const float* __restrict__ ln1_b,
    const float* __restrict__ ln2_g, const float* __restrict__ ln2_b,
    const float* __restrict__ ff1_w, const float* __restrict__ ff1_b,
    const float* __restrict__ ff2_w, const float* __restrict__ ff2_b,
    const float* __restrict__ fin_g, const float* __restrict__ fin_b,
    const float* __restrict__ hw1, const float* __restrict__ hb1,
    const float* __restrict__ hlg, const float* __restrict__ hlb,
    const float* __restrict__ hw2, const float* __restrict__ hb2,
    float* __restrict__ out){
  __shared__ __align__(16) float tok[NT][H];
  __shared__ __align__(16) float hl[NT][H];
  __shared__ __align__(16) float big[NT][512];
  __shared__ float r[8];
  const int tid=threadIdx.x;
  const int h=tid&127;
  const int tg=tid>>7;         // token half: 0 -> tokens 0..15, 1 -> 16..31
  const int node0=blockIdx.x*NB;

  for (int i=tid; i<NT*H; i+=256){
    int t=i>>7, d=i&127;
    tok[t][d]=tokens[(size_t)(node0*4+t)*H+d]+hop_emb[(t&3)*H+d];
  }
  __syncthreads();

  for (int l=0;l<2;l++){
    // ---- LN1 -> hl
    { const float* g1=ln1_g+l*H; const float* b1=ln1_b+l*H;
      for (int t=tg; t<NT; t+=2){
        float v=tok[t][h];
        float s,ss; grpred2(v,v*v,s,ss,r,tid);
        float m=s*(1.f/H), var=ss*(1.f/H)-m*m;
        hl[t][h]=(v-m)*rsqrtf(var+1e-5f)*g1[h]+b1[h];
      }
    }
    __syncthreads();
    // ---- QKV -> big[t][0..384)
    { const float* W=qkv_w+(size_t)l*384*H;
      const float* B=qkv_b+(size_t)l*384;
      for (int jj=0;jj<3;jj++){
        int j=jj*128+h;
        const float4* wr=(const float4*)(W+(size_t)j*H);
        float bias=B[j];
        float acc[16];
        #pragma unroll
        for (int t=0;t<16;t++) acc[t]=bias;
        #pragma unroll 4
        for (int d4=0;d4<32;d4++){
          float4 w4=wr[d4];
          #pragma unroll
          for (int t=0;t<16;t++){
            float4 xv=((const float4*)hl[tg*16+t])[d4];
            acc[t]+=dot4(w4,xv);
          }
        }
        #pragma unroll
        for (int t=0;t<16;t++) big[tg*16+t][j]=acc[t];
      }
    }
    __syncthreads();
    // ---- attention: o -> hl (overwrites LN output, no longer needed)
    { int grp16=tid>>4, lane=tid&15;
      for (int pp=0;pp<4;pp++){
        int pair=grp16+16*pp;          // 0..63 = node(3b) x head(3b)
        int nl=pair>>3, hh=pair&7;
        int t0=nl*4, qd=hh*16+lane;
        float sc[4][4];
        #pragma unroll
        for (int s=0;s<4;s++){
          #pragma unroll
          for (int u=0;u<4;u++){
            float p=big[t0+s][qd]*big[t0+u][128+qd];
            p+=__shfl_xor(p,8); p+=__shfl_xor(p,4); p+=__shfl_xor(p,2); p+=__shfl_xor(p,1);
            sc[s][u]=p*0.25f;          // scale = 1/sqrt(16)
          }
        }
        #pragma unroll
        for (int s=0;s<4;s++){
          float m=fmaxf(fmaxf(sc[s][0],sc[s][1]),fmaxf(sc[s][2],sc[s][3]));
          float e0=__expf(sc[s][0]-m), e1=__expf(sc[s][1]-m),
                e2=__expf(sc[s][2]-m), e3=__expf(sc[s][3]-m);
          float inv=1.f/(e0+e1+e2+e3);
          float o=(e0*big[t0+0][256+qd]+e1*big[t0+1][256+qd]
                  +e2*big[t0+2][256+qd]+e3*big[t0+3][256+qd])*inv;
          hl[t0+s][qd]=o;
        }
      }
    }
    __syncthreads();
    // ---- out proj + residual: tok += o @ W^T + b
    { const float* W=out_w+(size_t)l*H*H;
      const float* B=out_b+(size_t)l*H;
      const float4* wr=(const float4*)(W+(size_t)h*H);
      float bias=B[h];
      float acc[16];
      #pragma unroll
      for (int t=0;t<16;t++) acc[t]=bias;
      #pragma unroll 4
      for (int d4=0;d4<32;d4++){
        float4 w4=wr[d4];
        #pragma unroll
        for (int t=0;t<16;t++){
          float4 xv=((const float4*)hl[tg*16+t])[d4];
          acc[t]+=dot4(w4,xv);
        }
      }
      #pragma unroll
      for (int t=0;t<16;t++) tok[tg*16+t][h]+=acc[t];
    }
    __syncthreads();
    // ---- LN2 -> hl
    { const float* g2=ln2_g+l*H; const float* b2=ln2_b+l*H;
      for (int t=tg; t<NT; t+=2){
        float v=tok[t][h];
        float s,ss; grpred2(v,v*v,s,ss,r,tid);
        float m=s*(1.f/H), var=ss*(1.f/H)-m*m;
        hl[t][h]=(v-m)*rsqrtf(var+1e-5f)*g2[h]+b2[h];
      }
    }
    __syncthreads();
    // ---- FF1 (relu) -> big[t][0..512)
    { const float* W=ff1_w+(size_t)l*512*H;
      const float* B=ff1_b+(size_t)l*512;
      for (int jj=0;jj<4;jj++){
        int j=jj*128+h;
        const float4* wr=(const float4*)(W+(size_t)j*H);
        float bias=B[j];
        float acc[16];
        #pragma unroll
        for (int t=0;t<16;t++) acc[t]=bias;
        #pragma unroll 4
        for (int d4=0;d4<32;d4++){
          float4 w4=wr[d4];
          #pragma unroll
          for (int t=0;t<16;t++){
            float4 xv=((const float4*)hl[tg*16+t])[d4];
            acc[t]+=dot4(w4,xv);
          }
        }
        #pragma unroll
        for (int t=0;t<16;t++) big[tg*16+t][j]=fmaxf(acc[t],0.f);
      }
    }
    __syncthreads();
    // ---- FF2 + residual: tok += big @ W^T + b
    { const float* W=ff2_w+(size_t)l*H*512;
      const float* B=ff2_b+(size_t)l*H;
      const float4* wr=(const float4*)(W+(size_t)h*512);
      float bias=B[h];
      float acc[16];
      #pragma unroll
      for (int t=0;t<16;t++) acc[t]=bias;
      #pragma unroll 4
      for (int d4=0;d4<128;d4++){
        float4 w4=wr[d4];
        #pragma unroll
        for (int t=0;t<16;t++){
          float4 xv=((const float4*)big[tg*16+t])[d4];
          acc[t]+=dot4(w4,xv);
        }
      }
      #pragma unroll
      for (int t=0;t<16;t++) tok[tg*16+t][h]+=acc[t];
    }
    __syncthreads();
  }

  // ---- head: final LN (token 0) -> gelu(W1) -> LN -> W2 (each 128-group does 4 nodes)
  for (int nl=tg; nl<NB; nl+=2){
    int t=nl*4;
    float v=tok[t][h];
    float s,ss; grpred2(v,v*v,s,ss,r,tid);
    float m=s*(1.f/H), var=ss*(1.f/H)-m*m;
    float fvl=(v-m)*rsqrtf(var+1e-5f)*fin_g[h]+fin_b[h];
    __syncthreads();
    big[nl][h]=fvl;
    __syncthreads();
    float acc=hb1[h];
    { const float4* wr=(const float4*)(hw1+(size_t)h*H);
      const float4* xv=(const float4*)big[nl];
      #pragma unroll 4
      for (int d4=0;d4<32;d4++) acc+=dot4(wr[d4],xv[d4]); }
    float ge=0.5f*acc*(1.0f+erff(acc*0.70710678118654752f));
    float s2,ss2; grpred2(ge,ge*ge,s2,ss2,r,tid);
    float m2=s2*(1.f/H), v2=ss2*(1.f/H)-m2*m2;
    float z=(ge-m2)*rsqrtf(v2+1e-5f)*hlg[h]+hlb[h];
    __syncthreads();
    big[nl][h]=z;
    __syncthreads();
    if (h<10){
      float a2=hb2[h];
      const float* w2r=hw2+(size_t)h*H;
      #pragma unroll 4
      for (int d=0;d<H;d++) a2+=big[nl][d]*w2r[d];
      out[(size_t)(node0+nl)*10+h]=a2;
    }
  }
}

extern "C" void kernel_launch(void* const* d_in, const int* in_sizes, int n_in,
                              void* d_out, int out_size, void* d_ws, size_t ws_size,
                              hipStream_t stream){
  const float* x       =(const float*)d_in[0];
  const int*   ei      =(const int*)  d_in[1];
  const float* eigvecs =(const float*)d_in[2];
  const float* eigvals =(const float*)d_in[3];
  const float* enc_w   =(const float*)d_in[4];
  const float* enc_b   =(const float*)d_in[5];
  const float* in_ln_g =(const float*)d_in[6];
  const float* in_ln_b =(const float*)d_in[7];
  const float* pe_phi_w1=(const float*)d_in[8];
  const float* pe_phi_w2=(const float*)d_in[9];
  const float* pe_rho_w1=(const float*)d_in[10];
  const float* pe_rho_b1=(const float*)d_in[11];
  const float* pe_rho_w2=(const float*)d_in[12];
  const float* pe_rho_b2=(const float*)d_in[13];
  const float* pe_eps  =(const float*)d_in[14];
  const float* hop_emb =(const float*)d_in[15];
  const float* qkv_w   =(const float*)d_in[16];
  const float* qkv_b   =(const float*)d_in[17];
  const float* out_w   =(const float*)d_in[18];
  const float* out_b   =(const float*)d_in[19];
  const float* ln1_g   =(const float*)d_in[20];
  const float* ln1_b   =(const float*)d_in[21];
  const float* ln2_g   =(const float*)d_in[22];
  const float* ln2_b   =(const float*)d_in[23];
  const float* ff1_w   =(const float*)d_in[24];
  const float* ff1_b   =(const float*)d_in[25];
  const float* ff2_w   =(const float*)d_in[26];
  const float* ff2_b   =(const float*)d_in[27];
  const float* fin_g   =(const float*)d_in[28];
  const float* fin_b   =(const float*)d_in[29];
  const float* hw1     =(const float*)d_in[30];
  const float* hb1     =(const float*)d_in[31];
  const float* hlg     =(const float*)d_in[32];
  const float* hlb     =(const float*)d_in[33];
  const float* hw2     =(const float*)d_in[34];
  const float* hb2     =(const float*)d_in[35];

  char* ws=(char*)d_ws;
  size_t off=0;
  auto alloc=[&](size_t bytes)->void*{
    void* p=ws+off;
    off+=(bytes+255)&~(size_t)255;
    return p;
  };
  float* tokens =(float*)alloc((size_t)NN*4*H*sizeof(float));   // 204.8 MB
  float* deg    =(float*)alloc((size_t)NN*sizeof(float));       // becomes dinv
  int*   counts =(int*)  alloc((size_t)NN*sizeof(int));
  int*   row_ptr=(int*)  alloc((size_t)(NN+1)*sizeof(int));
  int*   cursor =(int*)  alloc((size_t)NN*sizeof(int));
  int*   cs_col =(int*)  alloc((size_t)EE*sizeof(int));
  float* cs_w   =(float*)alloc((size_t)EE*sizeof(float));
  int*   flag   =(int*)  alloc(256);
  if (off>ws_size) return; // workspace insufficient (would need ~219 MB)

  hipMemsetAsync(deg,0,(size_t)NN*sizeof(float),stream);
  hipMemsetAsync(counts,0,(size_t)NN*sizeof(int),stream);
  detect_kernel<<<1,256,0,stream>>>(ei,flag);
  enc_kernel<<<NN/2,256,0,stream>>>(x,enc_w,enc_b,in_ln_g,in_ln_b,tokens);
  hist_kernel<<<(EE+255)/256,256,0,stream>>>(ei,flag,deg,counts);
  dinv_kernel<<<(NN+255)/256,256,0,stream>>>(deg);
  scan_kernel<<<1,1024,0,stream>>>(counts,row_ptr,cursor);
  scatter_kernel<<<(EE+255)/256,256,0,stream>>>(ei,flag,cursor,deg,cs_col,cs_w);
  for (int k=0;k<3;k++)
    spmm_kernel<<<NN/2,256,0,stream>>>(tokens,row_ptr,cs_col,cs_w,k);
  pe_kernel<<<NN/2,256,0,stream>>>(eigvecs,eigvals,pe_phi_w1,pe_phi_w2,
                                   pe_rho_w1,pe_rho_b1,pe_rho_w2,pe_rho_b2,
                                   pe_eps,tokens);
  xform_kernel<<<NN/NB,256,0,stream>>>(tokens,hop_emb,qkv_w,qkv_b,out_w,out_b,
                                       ln1_g,ln1_b,ln2_g,ln2_b,ff1_w,ff1_b,ff2_w,ff2_b,
                                       fin_g,fin_b,hw1,hb1,hlg,hlb,hw2,hb2,
                                       (float*)d_out);
}

// Round 2
// 5212.465 us; speedup vs baseline: 4.5309x; 4.5309x over previous
//
#include <hip/hip_runtime.h>
#include <cmath>

#define NN 100000
#define EE 1600000
#define H 128
#define PP 16
#define S1 136   // hlb stride (halfwords)
#define S2 392   // qkvb stride (halfwords)

typedef __attribute__((ext_vector_type(8))) short bf16x8;
typedef __attribute__((ext_vector_type(4))) float f32x4;

__device__ __forceinline__ float dot4(float4 a, float4 b){
  return a.x*b.x + a.y*b.y + a.z*b.z + a.w*b.w;
}
__device__ __forceinline__ float wred64(float v){
  v += __shfl_xor(v,32); v += __shfl_xor(v,16); v += __shfl_xor(v,8);
  v += __shfl_xor(v,4);  v += __shfl_xor(v,2);  v += __shfl_xor(v,1);
  return v;
}
__device__ __forceinline__ void grpred2(float a, float b, float& oa, float& ob, float* r, int tid){
  float sa=wred64(a), sb=wred64(b);
  int w=tid>>6;
  __syncthreads();
  if ((tid&63)==0){ r[w*2]=sa; r[w*2+1]=sb; }
  __syncthreads();
  int g2=(tid>>7)*2;
  oa=r[g2*2]+r[g2*2+2];
  ob=r[g2*2+1]+r[g2*2+3];
}
__device__ __forceinline__ ushort f2b(float f){
  union{float f; unsigned u;} x; x.f=f;
  unsigned r=(x.u + 0x7fffu + ((x.u>>16)&1u))>>16;
  return (ushort)r;
}
__device__ __forceinline__ float b2f(ushort h){
  union{unsigned u; float f;} x; x.u=((unsigned)h)<<16; return x.f;
}

// ---- weight fp32 -> bf16 conversion
__global__ void cvtw_kernel(const float* __restrict__ src, ushort* __restrict__ dst, int n){
  int i=blockIdx.x*256+threadIdx.x;
  if (i<n) dst[i]=f2b(src[i]);
}

// ---- edge_index dtype detect: flag=1 if int64 (odd words all zero), else 0
__global__ void detect_kernel(const int* __restrict__ ei, int* __restrict__ flag){
  __shared__ int nz;
  if (threadIdx.x==0) nz=0;
  __syncthreads();
  for (int i=threadIdx.x; i<2048; i+=256){
    if (ei[2*i+1]!=0) nz=1;
  }
  __syncthreads();
  if (threadIdx.x==0) flag[0] = nz ? 0 : 1;
}

// ---- encoder: tokens[n,0,:] = LN(x @ enc_w^T + enc_b)
__global__ __launch_bounds__(256) void enc_kernel(
    const float* __restrict__ x, const float* __restrict__ w, const float* __restrict__ b,
    const float* __restrict__ g, const float* __restrict__ bb, float* __restrict__ tokens){
  __shared__ __align__(16) float xs[2][H];
  __shared__ float r[8];
  int tid=threadIdx.x, h=tid&127, tg=tid>>7;
  int n=blockIdx.x*2+tg;
  xs[tg][h]=x[(size_t)n*H+h];
  __syncthreads();
  float acc=b[h];
  const float4* wr=(const float4*)(w+(size_t)h*H);
  const float4* xv=(const float4*)xs[tg];
  #pragma unroll 4
  for (int d4=0; d4<32; d4++) acc += dot4(wr[d4], xv[d4]);
  float s,ss; grpred2(acc, acc*acc, s, ss, r, tid);
  float m=s*(1.f/H), var=ss*(1.f/H)-m*m;
  tokens[(size_t)n*4*H+h] = (acc-m)*rsqrtf(var+1e-5f)*g[h]+bb[h];
}

// ---- histograms: deg over col (float), counts over row (int)
__global__ void hist_kernel(const int* __restrict__ ei, const int* __restrict__ flag,
                            float* __restrict__ deg, int* __restrict__ counts){
  int f=flag[0];
  int e=blockIdx.x*256+threadIdx.x;
  if (e>=EE) return;
  int rw=ei[(size_t)e<<f];
  int cl=ei[((size_t)EE+e)<<f];
  atomicAdd(&counts[rw],1);
  atomicAdd(&deg[cl],1.0f);
}

__global__ void dinv_kernel(float* __restrict__ deg){
  int i=blockIdx.x*256+threadIdx.x;
  if (i<NN) deg[i]=rsqrtf(fmaxf(deg[i],1.0f));
}

// ---- single-block exclusive scan of counts -> row_ptr, cursor
__global__ __launch_bounds__(1024) void scan_kernel(const int* __restrict__ counts,
                                                    int* __restrict__ row_ptr, int* __restrict__ cursor){
  __shared__ int wsum_s[16];
  __shared__ int carry_s;
  int tid=threadIdx.x, lane=tid&63, w=tid>>6;
  if (tid==0) carry_s=0;
  __syncthreads();
  for (int base=0; base<NN; base+=1024){
    int i=base+tid;
    int v=(i<NN)?counts[i]:0;
    int x=v;
    for (int off=1; off<64; off<<=1){
      int t=__shfl_up(x,off);
      if (lane>=off) x+=t;
    }
    if (lane==63) wsum_s[w]=x;
    __syncthreads();
    int woff=0;
    #pragma unroll
    for (int ww=0; ww<16; ww++) if (ww<w) woff+=wsum_s[ww];
    int carry=carry_s;
    int excl=carry+woff+x-v;
    if (i<NN){ row_ptr[i]=excl; cursor[i]=excl; }
    __syncthreads();
    if (tid==1023) carry_s = carry + woff + x;
    __syncthreads();
  }
  if (tid==0) row_ptr[NN]=carry_s;
}

// ---- scatter edges into CSR (col + weight)
__global__ void scatter_kernel(const int* __restrict__ ei, const int* __restrict__ flag,
                               int* __restrict__ cursor, const float* __restrict__ dinv,
                               int* __restrict__ cs_col, float* __restrict__ cs_w){
  int f=flag[0];
  int e=blockIdx.x*256+threadIdx.x;
  if (e>=EE) return;
  int rw=ei[(size_t)e<<f];
  int cl=ei[((size_t)EE+e)<<f];
  int pos=atomicAdd(&cursor[rw],1);
  cs_col[pos]=cl;
  cs_w[pos]=dinv[rw]*dinv[cl];
}

// ---- SpMM hop: tokens[:,k+1,:] = A_norm @ tokens[:,k,:]
__global__ __launch_bounds__(256) void spmm_kernel(float* __restrict__ tokens,
    const int* __restrict__ row_ptr, const int* __restrict__ cs_col,
    const float* __restrict__ cs_w, int k){
  int tid=threadIdx.x;
  int n=blockIdx.x*2+(tid>>7);
  int t=tid&127;
  int beg=row_ptr[n], end=row_ptr[n+1];
  float acc=0.f;
  const float* src=tokens+(size_t)k*H+t;
  for (int j=beg;j<end;j++){
    acc += cs_w[j]*src[(size_t)cs_col[j]*(4*H)];
  }
  tokens[((size_t)n*4+k+1)*H+t]=acc;
}

// ---- PE: tokens[n,0,:] += rho(sum_p relu(phi))
__global__ __launch_bounds__(256) void pe_kernel(
    const float* __restrict__ eigvecs, const float* __restrict__ eigvals,
    const float* __restrict__ phi_w1, const float* __restrict__ phi_w2,
    const float* __restrict__ rho_w1, const float* __restrict__ rho_b1,
    const float* __restrict__ rho_w2, const float* __restrict__ rho_b2,
    const float* __restrict__ pe_eps, float* __restrict__ tokens){
  __shared__ __align__(16) float fe[2][PP][2];
  __shared__ __align__(16) float sb[2][H];
  int tid=threadIdx.x, h=tid&127, tg=tid>>7;
  int n=blockIdx.x*2+tg;
  if (h<PP){
    float a=eigvecs[(size_t)n*PP+h];
    float b=eigvals[(size_t)n*PP+h]+pe_eps[h];
    fe[tg][h][0]=isnan(a)?0.f:a;
    fe[tg][h][1]=isnan(b)?0.f:b;
  }
  __syncthreads();
  float wa=phi_w1[h*2], wb=phi_w1[h*2+1];
  float sp=0.f;
  #pragma unroll
  for (int p=0;p<PP;p++){
    float fv=fe[tg][p][0]*wa+fe[tg][p][1]*wb;
    sp += fmaxf(fv,0.f);
  }
  sb[tg][h]=sp;
  __syncthreads();
  float s=0.f;
  { const float4* wr=(const float4*)(phi_w2+(size_t)h*H);
    const float4* xv=(const float4*)sb[tg];
    #pragma unroll 4
    for (int d4=0;d4<32;d4++) s+=dot4(wr[d4],xv[d4]); }
  __syncthreads();
  sb[tg][h]=s;
  __syncthreads();
  float t1=rho_b1[h];
  { const float4* wr=(const float4*)(rho_w1+(size_t)h*H);
    const float4* xv=(const float4*)sb[tg];
    #pragma unroll 4
    for (int d4=0;d4<32;d4++) t1+=dot4(wr[d4],xv[d4]); }
  t1=fmaxf(t1,0.f);
  __syncthreads();
  sb[tg][h]=t1;
  __syncthreads();
  float pe=rho_b2[h];
  { const float4* wr=(const float4*)(rho_w2+(size_t)h*H);
    const float4* xv=(const float4*)sb[tg];
    #pragma unroll 4
    for (int d4=0;d4<32;d4++) pe+=dot4(wr[d4],xv[d4]); }
  tokens[(size_t)n*4*H+h] += pe;
}

// ---- in-register LN for a wave's 16-row stripe (fp32), write bf16 to hb
__device__ __forceinline__ void ln_block(const float (&tk)[8][4], ushort* hb,
                                         const float* g, const float* bta,
                                         int rowb, int l15){
  float gv[8], bv[8];
  #pragma unroll
  for (int nt=0;nt<8;nt++){ gv[nt]=g[nt*16+l15]; bv[nt]=bta[nt*16+l15]; }
  #pragma unroll
  for (int reg=0;reg<4;reg++){
    float s=0.f,q=0.f;
    #pragma unroll
    for (int nt=0;nt<8;nt++){ float v=tk[nt][reg]; s+=v; q+=v*v; }
    #pragma unroll
    for (int m=1;m<16;m<<=1){ s+=__shfl_xor(s,m); q+=__shfl_xor(q,m); }
    float mean=s*(1.f/128.f);
    float rs=rsqrtf(q*(1.f/128.f)-mean*mean+1e-5f);
    int row=rowb+reg;
    #pragma unroll
    for (int nt=0;nt<8;nt++){
      float hv=(tk[nt][reg]-mean)*rs*gv[nt]+bv[nt];
      hb[row*S1 + nt*16+l15]=f2b(hv);
    }
  }
}

// ---- fused MFMA transformer (2 layers) + head. 32 nodes (128 token-rows)/block.
// 8 waves; wave w owns token rows [w*16, w*16+16); residual fp32 in registers:
// tokacc[nt][reg] -> row = w*16 + (lane>>4)*4 + reg, col = nt*16 + (lane&15)
__global__ __launch_bounds__(512,2) void xform2_kernel(
    const float* __restrict__ tokens, const float* __restrict__ hop_emb,
    const ushort* __restrict__ wqkv, const float* __restrict__ qkv_b,
    const ushort* __restrict__ wout, const float* __restrict__ out_b,
    const float* __restrict__ ln1_g, const float* __restrict__ ln1_b,
    const float* __restrict__ ln2_g, const float* __restrict__ ln2_b,
    const ushort* __restrict__ wff1, const float* __restrict__ ff1_b,
    const ushort* __restrict__ wff2, const float* __restrict__ ff2_b,
    const float* __restrict__ fin_g, const float* __restrict__ fin_b,
    const ushort* __restrict__ hw1b, const float* __restrict__ hb1,
    const float* __restrict__ hlng, const float* __restrict__ hlnb,
    const ushort* __restrict__ hw2b, const float* __restrict__ hb2,
    float* __restrict__ out){
  __shared__ __align__(16) ushort hlb[128*S1];    // 34816 B : A-operand staging
  __shared__ __align__(16) ushort qkvb[128*S2];   // 100352 B: QKV out / FF chunk+Wstage
  __shared__ float red_s[32*8], red_q[32*8], stat_m[32], stat_r[32];
  ushort* chunkA = qkvb;              // [128][S1] FF1 chunk output
  ushort* wstage = qkvb + 128*S1;     // [128][S1] FF2 weight slice

  const int tid=threadIdx.x;
  const int wid=tid>>6;
  const int l=tid&63, l15=l&15, l4=(l>>4)&3;
  const int node0=blockIdx.x*32;
  const int rowb=wid*16 + l4*4;

  // load residual + hop_emb into registers
  float tokacc[8][4];
  const float* tg=tokens + ((size_t)node0*4 + rowb)*H;
  #pragma unroll
  for (int nt=0;nt<8;nt++){
    int col=nt*16+l15;
    #pragma unroll
    for (int reg=0;reg<4;reg++)
      tokacc[nt][reg]=tg[reg*H+col] + hop_emb[reg*H+col];
  }

  for (int ll=0;ll<2;ll++){
    // LN1 -> hlb (bf16)
    ln_block(tokacc, hlb, ln1_g+ll*H, ln1_b+ll*H, rowb, l15);
    __syncthreads();

    // QKV GEMM: C[128x384] = hlb @ Wqkv^T ; wave w does Ntiles {w, w+8, w+16}
    { const ushort* Wl=wqkv + (size_t)ll*384*H;
      bf16x8 bq[3][4]; float bias[3]; int ncol[3];
      #pragma unroll
      for (int j=0;j<3;j++){
        int n=(wid+j*8)*16+l15; ncol[j]=n;
        bias[j]=qkv_b[ll*384+n];
        #pragma unroll
        for (int kk=0;kk<4;kk++)
          bq[j][kk]=*(const bf16x8*)(Wl + (size_t)n*H + kk*32 + l4*8);
      }
      for (int mt=0;mt<8;mt++){
        f32x4 c0={0.f,0.f,0.f,0.f}, c1={0.f,0.f,0.f,0.f}, c2={0.f,0.f,0.f,0.f};
        #pragma unroll
        for (int kk=0;kk<4;kk++){
          bf16x8 a=*(const bf16x8*)(hlb + (mt*16+l15)*S1 + kk*32 + l4*8);
          c0=__builtin_amdgcn_mfma_f32_16x16x32_bf16(a,bq[0][kk],c0,0,0,0);
          c1=__builtin_amdgcn_mfma_f32_16x16x32_bf16(a,bq[1][kk],c1,0,0,0);
          c2=__builtin_amdgcn_mfma_f32_16x16x32_bf16(a,bq[2][kk],c2,0,0,0);
        }
        int rb=mt*16+l4*4;
        #pragma unroll
        for (int reg=0;reg<4;reg++){
          qkvb[(rb+reg)*S2+ncol[0]]=f2b(c0[reg]+bias[0]);
          qkvb[(rb+reg)*S2+ncol[1]]=f2b(c1[reg]+bias[1]);
          qkvb[(rb+reg)*S2+ncol[2]]=f2b(c2[reg]+bias[2]);
        }
      }
    }
    __syncthreads();

    // attention: wave w -> nodes w*4..w*4+3 (its own stripe rows), o -> hlb
    for (int p=0;p<8;p++){
      int idx=p*4+l4;              // 0..31 = nodeLocal(2b)<<3 | head(3b)
      int nloc=idx>>3, hh=idx&7;
      int r0=wid*16+nloc*4;
      int cq=hh*16+l15;
      float qv[4],kv[4],vv[4];
      #pragma unroll
      for (int s4=0;s4<4;s4++){
        qv[s4]=b2f(qkvb[(r0+s4)*S2+cq]);
        kv[s4]=b2f(qkvb[(r0+s4)*S2+128+cq]);
        vv[s4]=b2f(qkvb[(r0+s4)*S2+256+cq]);
      }
      float sc[4][4];
      #pragma unroll
      for (int s4=0;s4<4;s4++){
        #pragma unroll
        for (int u=0;u<4;u++){
          float pp=qv[s4]*kv[u];
          pp+=__shfl_xor(pp,1); pp+=__shfl_xor(pp,2);
          pp+=__shfl_xor(pp,4); pp+=__shfl_xor(pp,8);
          sc[s4][u]=pp*0.25f;
        }
      }
      #pragma unroll
      for (int s4=0;s4<4;s4++){
        float m=fmaxf(fmaxf(sc[s4][0],sc[s4][1]),fmaxf(sc[s4][2],sc[s4][3]));
        float e0=__expf(sc[s4][0]-m), e1=__expf(sc[s4][1]-m),
              e2=__expf(sc[s4][2]-m), e3=__expf(sc[s4][3]-m);
        float inv=1.f/(e0+e1+e2+e3);
        float o=(e0*vv[0]+e1*vv[1]+e2*vv[2]+e3*vv[3])*inv;
        hlb[(r0+s4)*S1+cq]=f2b(o);
      }
    }
    __syncthreads();

    // out-proj: wave-local Mtile=w; tokacc += o @ Wout^T + b
    { const ushort* Wl=wout + (size_t)ll*H*H;
      bf16x8 a[4];
      #pragma unroll
      for (int kk=0;kk<4;kk++)
        a[kk]=*(const bf16x8*)(hlb + (wid*16+l15)*S1 + kk*32 + l4*8);
      #pragma unroll
      for (int nt=0;nt<8;nt++){
        int n=nt*16+l15;
        f32x4 c={0.f,0.f,0.f,0.f};
        #pragma unroll
        for (int kk=0;kk<4;kk++){
          bf16x8 bb=*(const bf16x8*)(Wl + (size_t)n*H + kk*32 + l4*8);
          c=__builtin_amdgcn_mfma_f32_16x16x32_bf16(a[kk],bb,c,0,0,0);
        }
        float bias=out_b[ll*H+n];
        #pragma unroll
        for (int reg=0;reg<4;reg++) tokacc[nt][reg]+=c[reg]+bias;
      }
    }

    // LN2 -> hlb (wave-local stripe; safe: all hlb consumers of 'o' were wave-local)
    ln_block(tokacc, hlb, ln2_g+ll*H, ln2_b+ll*H, rowb, l15);
    __syncthreads();

    // FF: 4 K-chunks of 128; FF1 -> chunkA (relu,bf16); FF2 accumulates fac
    { const ushort* w1l=wff1 + (size_t)ll*512*H;
      const ushort* w2l=wff2 + (size_t)ll*H*512;
      f32x4 fac[8];
      #pragma unroll
      for (int nt=0;nt<8;nt++) fac[nt]=(f32x4){0.f,0.f,0.f,0.f};
      for (int c0=0;c0<4;c0++){
        // cooperative stage of Wff2[:, c0*128 : c0*128+128) into wstage
        { int rr=tid>>2, seg=tid&3;
          #pragma unroll
          for (int i=0;i<4;i++)
            *(bf16x8*)(wstage + rr*S1 + seg*32 + i*8) =
              *(const bf16x8*)(w2l + (size_t)rr*512 + c0*128 + seg*32 + i*8);
        }
        // FF1: wave w computes global Ntile c0*8+w -> chunkA cols w*16..
        { int n=(c0*8+wid)*16+l15;
          bf16x8 b1[4];
          #pragma unroll
          for (int kk=0;kk<4;kk++)
            b1[kk]=*(const bf16x8*)(w1l + (size_t)n*H + kk*32 + l4*8);
          float bias1=ff1_b[ll*512+n];
          for (int mt=0;mt<8;mt++){
            f32x4 c={0.f,0.f,0.f,0.f};
            #pragma unroll
            for (int kk=0;kk<4;kk++){
              bf16x8 a=*(const bf16x8*)(hlb + (mt*16+l15)*S1 + kk*32 + l4*8);
              c=__builtin_amdgcn_mfma_f32_16x16x32_bf16(a,b1[kk],c,0,0,0);
            }
            int rb=mt*16+l4*4;
            #pragma unroll
            for (int reg=0;reg<4;reg++)
              chunkA[(rb+reg)*S1 + wid*16+l15]=f2b(fmaxf(c[reg]+bias1,0.f));
          }
        }
        __syncthreads();
        // FF2 partial: A = chunkA wave-local stripe; B = wstage
        { bf16x8 a2[4];
          #pragma unroll
          for (int kk=0;kk<4;kk++)
            a2[kk]=*(const bf16x8*)(chunkA + (wid*16+l15)*S1 + kk*32 + l4*8);
          #pragma unroll
          for (int nt=0;nt<8;nt++){
            int n2=nt*16+l15;
            #pragma unroll
            for (int kk=0;kk<4;kk++){
              bf16x8 bb=*(const bf16x8*)(wstage + n2*S1 + kk*32 + l4*8);
              fac[nt]=__builtin_amdgcn_mfma_f32_16x16x32_bf16(a2[kk],bb,fac[nt],0,0,0);
            }
          }
        }
        __syncthreads();
      }
      #pragma unroll
      for (int nt=0;nt<8;nt++){
        float b2v=ff2_b[ll*H + nt*16+l15];
        #pragma unroll
        for (int reg=0;reg<4;reg++) tokacc[nt][reg]+=fac[nt][reg]+b2v;
      }
    }
  }

  // ---- final LN on token-0 rows (reg==0 slots), compact to hlb rows 0..31
  { float s=0.f,q=0.f;
    #pragma unroll
    for (int nt=0;nt<8;nt++){ float v=tokacc[nt][0]; s+=v; q+=v*v; }
    #pragma unroll
    for (int m=1;m<16;m<<=1){ s+=__shfl_xor(s,m); q+=__shfl_xor(q,m); }
    float mean=s*(1.f/128.f);
    float rs=rsqrtf(q*(1.f/128.f)-mean*mean+1e-5f);
    int ci=wid*4+l4;       // compact node-local row 0..31
    #pragma unroll
    for (int nt=0;nt<8;nt++){
      int col=nt*16+l15;
      float hv=(tokacc[nt][0]-mean)*rs*fin_g[col]+fin_b[col];
      hlb[ci*S1+col]=f2b(hv);
    }
  }
  __syncthreads();

  // ---- head GEMM1 [32x128]@hw1^T + gelu
  float gel[2][4];
  { int n=wid*16+l15;
    bf16x8 bh[4];
    #pragma unroll
    for (int kk=0;kk<4;kk++)
      bh[kk]=*(const bf16x8*)(hw1b + (size_t)n*H + kk*32 + l4*8);
    float hb1v=hb1[n];
    #pragma unroll
    for (int mt=0;mt<2;mt++){
      f32x4 c={0.f,0.f,0.f,0.f};
      #pragma unroll
      for (int kk=0;kk<4;kk++){
        bf16x8 a=*(const bf16x8*)(hlb + (mt*16+l15)*S1 + kk*32 + l4*8);
        c=__builtin_amdgcn_mfma_f32_16x16x32_bf16(a,bh[kk],c,0,0,0);
      }
      #pragma unroll
      for (int reg=0;reg<4;reg++){
        float xx=c[reg]+hb1v;
        gel[mt][reg]=0.5f*xx*(1.f+erff(xx*0.70710678118654752f));
      }
    }
  }
  // ---- head LN (cross-wave: rows spread over waves' 16-col slices)
  #pragma unroll
  for (int mt=0;mt<2;mt++){
    #pragma unroll
    for (int reg=0;reg<4;reg++){
      float v=gel[mt][reg], sv=v, qv=v*v;
      #pragma unroll
      for (int m=1;m<16;m<<=1){ sv+=__shfl_xor(sv,m); qv+=__shfl_xor(qv,m); }
      if (l15==0){ int r32=mt*16+l4*4+reg; red_s[r32*8+wid]=sv; red_q[r32*8+wid]=qv; }
    }
  }
  __syncthreads();
  if (tid<32){
    float ss=0.f,qs=0.f;
    #pragma unroll
    for (int w=0;w<8;w++){ ss+=red_s[tid*8+w]; qs+=red_q[tid*8+w]; }
    float mm=ss*(1.f/128.f);
    stat_m[tid]=mm;
    stat_r[tid]=rsqrtf(qs*(1.f/128.f)-mm*mm+1e-5f);
  }
  __syncthreads();
  { int n=wid*16+l15;
    float hg=hlng[n], hbv=hlnb[n];
    #pragma unroll
    for (int mt=0;mt<2;mt++){
      #pragma unroll
      for (int reg=0;reg<4;reg++){
        int r32=mt*16+l4*4+reg;
        float z=(gel[mt][reg]-stat_m[r32])*stat_r[r32]*hg+hbv;
        hlb[r32*S1+n]=f2b(z);
      }
    }
  }
  __syncthreads();

  // ---- head GEMM2 [32x128] @ hw2^T -> out (waves 0,1)
  if (wid<2){
    int mt=wid;
    bool valid=l15<10;
    bf16x8 b2[4];
    #pragma unroll
    for (int kk=0;kk<4;kk++){
      if (valid) b2[kk]=*(const bf16x8*)(hw2b + (size_t)l15*H + kk*32 + l4*8);
      else { bf16x8 z; for (int t=0;t<8;t++) z[t]=0; b2[kk]=z; }
    }
    f32x4 c={0.f,0.f,0.f,0.f};
    #pragma unroll
    for (int kk=0;kk<4;kk++){
      bf16x8 a=*(const bf16x8*)(hlb + (mt*16+l15)*S1 + kk*32 + l4*8);
      c=__builtin_amdgcn_mfma_f32_16x16x32_bf16(a,b2[kk],c,0,0,0);
    }
    if (valid){
      float bb2=hb2[l15];
      #pragma unroll
      for (int reg=0;reg<4;reg++){
        int i=mt*16+l4*4+reg;
        out[((size_t)node0+i)*10 + l15]=c[reg]+bb2;
      }
    }
  }
}

extern "C" void kernel_launch(void* const* d_in, const int* in_sizes, int n_in,
                              void* d_out, int out_size, void* d_ws, size_t ws_size,
                              hipStream_t stream){
  const float* x       =(const float*)d_in[0];
  const int*   ei      =(const int*)  d_in[1];
  const float* eigvecs =(const float*)d_in[2];
  const float* eigvals =(const float*)d_in[3];
  const float* enc_w   =(const float*)d_in[4];
  const float* enc_b   =(const float*)d_in[5];
  const float* in_ln_g =(const float*)d_in[6];
  const float* in_ln_b =(const float*)d_in[7];
  const float* pe_phi_w1=(const float*)d_in[8];
  const float* pe_phi_w2=(const float*)d_in[9];
  const float* pe_rho_w1=(const float*)d_in[10];
  const float* pe_rho_b1=(const float*)d_in[11];
  const float* pe_rho_w2=(const float*)d_in[12];
  const float* pe_rho_b2=(const float*)d_in[13];
  const float* pe_eps  =(const float*)d_in[14];
  const float* hop_emb =(const float*)d_in[15];
  const float* qkv_w   =(const float*)d_in[16];
  const float* qkv_b   =(const float*)d_in[17];
  const float* out_w   =(const float*)d_in[18];
  const float* out_b   =(const float*)d_in[19];
  const float* ln1_g   =(const float*)d_in[20];
  const float* ln1_b   =(const float*)d_in[21];
  const float* ln2_g   =(const float*)d_in[22];
  const float* ln2_b   =(const float*)d_in[23];
  const float* ff1_w   =(const float*)d_in[24];
  const float* ff1_b   =(const float*)d_in[25];
  const float* ff2_w   =(const float*)d_in[26];
  const float* ff2_b   =(const float*)d_in[27];
  const float* fin_g   =(const float*)d_in[28];
  const float* fin_b   =(const float*)d_in[29];
  const float* hw1     =(const float*)d_in[30];
  const float* hb1     =(const float*)d_in[31];
  const float* hlg     =(const float*)d_in[32];
  const float* hlb_    =(const float*)d_in[33];
  const float* hw2     =(const float*)d_in[34];
  const float* hb2     =(const float*)d_in[35];

  char* ws=(char*)d_ws;
  size_t off=0;
  auto alloc=[&](size_t bytes)->void*{
    void* p=ws+off;
    off+=(bytes+255)&~(size_t)255;
    return p;
  };
  float* tokens =(float*)alloc((size_t)NN*4*H*sizeof(float));   // 204.8 MB
  float* deg    =(float*)alloc((size_t)NN*sizeof(float));       // becomes dinv
  int*   counts =(int*)  alloc((size_t)NN*sizeof(int));
  int*   row_ptr=(int*)  alloc((size_t)(NN+1)*sizeof(int));
  int*   cursor =(int*)  alloc((size_t)NN*sizeof(int));
  int*   cs_col =(int*)  alloc((size_t)EE*sizeof(int));
  float* cs_w   =(float*)alloc((size_t)EE*sizeof(float));
  int*   flag   =(int*)  alloc(256);
  // bf16 weight copies
  ushort* wqkvb =(ushort*)alloc((size_t)2*384*H*sizeof(ushort));
  ushort* woutb =(ushort*)alloc((size_t)2*H*H*sizeof(ushort));
  ushort* wff1b =(ushort*)alloc((size_t)2*512*H*sizeof(ushort));
  ushort* wff2b =(ushort*)alloc((size_t)2*H*512*sizeof(ushort));
  ushort* hw1b  =(ushort*)alloc((size_t)H*H*sizeof(ushort));
  ushort* hw2b  =(ushort*)alloc((size_t)10*H*sizeof(ushort));
  if (off>ws_size) return; // workspace insufficient

  hipMemsetAsync(deg,0,(size_t)NN*sizeof(float),stream);
  hipMemsetAsync(counts,0,(size_t)NN*sizeof(int),stream);
  detect_kernel<<<1,256,0,stream>>>(ei,flag);
  // weight conversions
  cvtw_kernel<<<(2*384*H+255)/256,256,0,stream>>>(qkv_w,wqkvb,2*384*H);
  cvtw_kernel<<<(2*H*H+255)/256,256,0,stream>>>(out_w,woutb,2*H*H);
  cvtw_kernel<<<(2*512*H+255)/256,256,0,stream>>>(ff1_w,wff1b,2*512*H);
  cvtw_kernel<<<(2*H*512+255)/256,256,0,stream>>>(ff2_w,wff2b,2*H*512);
  cvtw_kernel<<<(H*H+255)/256,256,0,stream>>>(hw1,hw1b,H*H);
  cvtw_kernel<<<(10*H+255)/256,256,0,stream>>>(hw2,hw2b,10*H);

  enc_kernel<<<NN/2,256,0,stream>>>(x,enc_w,enc_b,in_ln_g,in_ln_b,tokens);
  hist_kernel<<<(EE+255)/256,256,0,stream>>>(ei,flag,deg,counts);
  dinv_kernel<<<(NN+255)/256,256,0,stream>>>(deg);
  scan_kernel<<<1,1024,0,stream>>>(counts,row_ptr,cursor);
  scatter_kernel<<<(EE+255)/256,256,0,stream>>>(ei,flag,cursor,deg,cs_col,cs_w);
  for (int k=0;k<3;k++)
    spmm_kernel<<<NN/2,256,0,stream>>>(tokens,row_ptr,cs_col,cs_w,k);
  pe_kernel<<<NN/2,256,0,stream>>>(eigvecs,eigvals,pe_phi_w1,pe_phi_w2,
                                   pe_rho_w1,pe_rho_b1,pe_rho_w2,pe_rho_b2,
                                   pe_eps,tokens);
  xform2_kernel<<<NN/32,512,0,stream>>>(tokens,hop_emb,
                                        wqkvb,qkv_b,woutb,out_b,
                                        ln1_g,ln1_b,ln2_g,ln2_b,
                                        wff1b,ff1_b,wff2b,ff2_b,
                                        fin_g,fin_b,hw1b,hb1,hlg,hlb_,hw2b,hb2,
                                        (float*)d_out);
}

// Round 4
// 3255.369 us; speedup vs baseline: 7.2549x; 1.6012x over previous
//
#include <hip/hip_runtime.h>
#include <cmath>

#define NN 100000
#define EE 1600000
#define H 128
#define PP 16
#define S1 136   // LDS A-stride (halfwords)
#define S2 392   // qkvb stride (halfwords)

typedef __attribute__((ext_vector_type(8))) short bf16x8;
typedef __attribute__((ext_vector_type(4))) float f32x4;

__device__ __forceinline__ float dot4(float4 a, float4 b){
  return a.x*b.x + a.y*b.y + a.z*b.z + a.w*b.w;
}
__device__ __forceinline__ float wred64(float v){
  v += __shfl_xor(v,32); v += __shfl_xor(v,16); v += __shfl_xor(v,8);
  v += __shfl_xor(v,4);  v += __shfl_xor(v,2);  v += __shfl_xor(v,1);
  return v;
}
__device__ __forceinline__ void grpred2(float a, float b, float& oa, float& ob, float* r, int tid){
  float sa=wred64(a), sb=wred64(b);
  int w=tid>>6;
  __syncthreads();
  if ((tid&63)==0){ r[w*2]=sa; r[w*2+1]=sb; }
  __syncthreads();
  int g2=(tid>>7)*2;
  oa=r[g2*2]+r[g2*2+2];
  ob=r[g2*2+1]+r[g2*2+3];
}
__device__ __forceinline__ ushort f2b(float f){
  union{float f; unsigned u;} x; x.f=f;
  unsigned r=(x.u + 0x7fffu + ((x.u>>16)&1u))>>16;
  return (ushort)r;
}
__device__ __forceinline__ float b2f(ushort h){
  union{unsigned u; float f;} x; x.u=((unsigned)h)<<16; return x.f;
}

// ---- weight fp32 -> bf16 conversion
__global__ void cvtw_kernel(const float* __restrict__ src, ushort* __restrict__ dst, int n){
  int i=blockIdx.x*256+threadIdx.x;
  if (i<n) dst[i]=f2b(src[i]);
}

// ---- edge_index dtype detect: flag=1 if int64 (odd words all zero), else 0
__global__ void detect_kernel(const int* __restrict__ ei, int* __restrict__ flag){
  __shared__ int nz;
  if (threadIdx.x==0) nz=0;
  __syncthreads();
  for (int i=threadIdx.x; i<2048; i+=256){
    if (ei[2*i+1]!=0) nz=1;
  }
  __syncthreads();
  if (threadIdx.x==0) flag[0] = nz ? 0 : 1;
}

// ---- encoder: tokens[n,0,:] = LN(x @ enc_w^T + enc_b)
__global__ __launch_bounds__(256) void enc_kernel(
    const float* __restrict__ x, const float* __restrict__ w, const float* __restrict__ b,
    const float* __restrict__ g, const float* __restrict__ bb, float* __restrict__ tokens){
  __shared__ __align__(16) float xs[2][H];
  __shared__ float r[8];
  int tid=threadIdx.x, h=tid&127, tg=tid>>7;
  int n=blockIdx.x*2+tg;
  xs[tg][h]=x[(size_t)n*H+h];
  __syncthreads();
  float acc=b[h];
  const float4* wr=(const float4*)(w+(size_t)h*H);
  const float4* xv=(const float4*)xs[tg];
  #pragma unroll 4
  for (int d4=0; d4<32; d4++) acc += dot4(wr[d4], xv[d4]);
  float s,ss; grpred2(acc, acc*acc, s, ss, r, tid);
  float m=s*(1.f/H), var=ss*(1.f/H)-m*m;
  tokens[(size_t)n*4*H+h] = (acc-m)*rsqrtf(var+1e-5f)*g[h]+bb[h];
}

// ---- histograms: deg over col (float), counts over row (int)
__global__ void hist_kernel(const int* __restrict__ ei, const int* __restrict__ flag,
                            float* __restrict__ deg, int* __restrict__ counts){
  int f=flag[0];
  int e=blockIdx.x*256+threadIdx.x;
  if (e>=EE) return;
  int rw=ei[(size_t)e<<f];
  int cl=ei[((size_t)EE+e)<<f];
  atomicAdd(&counts[rw],1);
  atomicAdd(&deg[cl],1.0f);
}

__global__ void dinv_kernel(float* __restrict__ deg){
  int i=blockIdx.x*256+threadIdx.x;
  if (i<NN) deg[i]=rsqrtf(fmaxf(deg[i],1.0f));
}

// ---- single-block exclusive scan of counts -> row_ptr, cursor
__global__ __launch_bounds__(1024) void scan_kernel(const int* __restrict__ counts,
                                                    int* __restrict__ row_ptr, int* __restrict__ cursor){
  __shared__ int wsum_s[16];
  __shared__ int carry_s;
  int tid=threadIdx.x, lane=tid&63, w=tid>>6;
  if (tid==0) carry_s=0;
  __syncthreads();
  for (int base=0; base<NN; base+=1024){
    int i=base+tid;
    int v=(i<NN)?counts[i]:0;
    int x=v;
    for (int off=1; off<64; off<<=1){
      int t=__shfl_up(x,off);
      if (lane>=off) x+=t;
    }
    if (lane==63) wsum_s[w]=x;
    __syncthreads();
    int woff=0;
    #pragma unroll
    for (int ww=0; ww<16; ww++) if (ww<w) woff+=wsum_s[ww];
    int carry=carry_s;
    int excl=carry+woff+x-v;
    if (i<NN){ row_ptr[i]=excl; cursor[i]=excl; }
    __syncthreads();
    if (tid==1023) carry_s = carry + woff + x;
    __syncthreads();
  }
  if (tid==0) row_ptr[NN]=carry_s;
}

// ---- scatter edges into CSR (col + weight)
__global__ void scatter_kernel(const int* __restrict__ ei, const int* __restrict__ flag,
                               int* __restrict__ cursor, const float* __restrict__ dinv,
                               int* __restrict__ cs_col, float* __restrict__ cs_w){
  int f=flag[0];
  int e=blockIdx.x*256+threadIdx.x;
  if (e>=EE) return;
  int rw=ei[(size_t)e<<f];
  int cl=ei[((size_t)EE+e)<<f];
  int pos=atomicAdd(&cursor[rw],1);
  cs_col[pos]=cl;
  cs_w[pos]=dinv[rw]*dinv[cl];
}

// ---- SpMM hop: tokens[:,k+1,:] = A_norm @ tokens[:,k,:]
__global__ __launch_bounds__(256) void spmm_kernel(float* __restrict__ tokens,
    const int* __restrict__ row_ptr, const int* __restrict__ cs_col,
    const float* __restrict__ cs_w, int k){
  int tid=threadIdx.x;
  int n=blockIdx.x*2+(tid>>7);
  int t=tid&127;
  int beg=row_ptr[n], end=row_ptr[n+1];
  float acc=0.f;
  const float* src=tokens+(size_t)k*H+t;
  for (int j=beg;j<end;j++){
    acc += cs_w[j]*src[(size_t)cs_col[j]*(4*H)];
  }
  tokens[((size_t)n*4+k+1)*H+t]=acc;
}

// ---- one 128x128 @ 128x128^T MFMA step (wave-local 16-row stripe)
__device__ __forceinline__ void pe_gemm(const ushort* Ain, const ushort* __restrict__ W,
                                        const float* __restrict__ bias, ushort* Aout,
                                        bool dorelu, int wid, int l15, int l4){
  bf16x8 a[4];
  #pragma unroll
  for (int kk=0;kk<4;kk++)
    a[kk]=*(const bf16x8*)(Ain + (wid*16+l15)*S1 + kk*32 + l4*8);
  #pragma unroll
  for (int nt=0;nt<8;nt++){
    int n=nt*16+l15;
    f32x4 c={0.f,0.f,0.f,0.f};
    #pragma unroll
    for (int kk=0;kk<4;kk++){
      bf16x8 bb=*(const bf16x8*)(W + (size_t)n*H + kk*32 + l4*8);
      c=__builtin_amdgcn_mfma_f32_16x16x32_bf16(a[kk],bb,c,0,0,0);
    }
    float bv=bias?bias[n]:0.f;
    int rb=wid*16+l4*4;
    #pragma unroll
    for (int reg=0;reg<4;reg++){
      float v=c[reg]+bv;
      if (dorelu) v=fmaxf(v,0.f);
      Aout[(rb+reg)*S1+n]=f2b(v);
    }
  }
}

// ---- PE via MFMA: 128 nodes/block, 8 waves, tokens[:,0,:] += rho(...)
__global__ __launch_bounds__(512) void pe2_kernel(
    const float* __restrict__ eigvecs, const float* __restrict__ eigvals,
    const float* __restrict__ phi_w1, const float* __restrict__ pe_eps,
    const ushort* __restrict__ wpw2,
    const ushort* __restrict__ wrw1, const float* __restrict__ rho_b1,
    const ushort* __restrict__ wrw2, const float* __restrict__ rho_b2,
    float* __restrict__ tokens){
  __shared__ __align__(16) ushort bufA[128*S1];
  __shared__ __align__(16) ushort bufB[128*S1];
  __shared__ float was[H], wbs[H], epss[PP];
  const int tid=threadIdx.x;
  const int wid=tid>>6;
  const int l=tid&63, l15=l&15, l4=(l>>4)&3;
  const int node0=blockIdx.x*128;

  if (tid<H){ was[tid]=phi_w1[tid*2]; wbs[tid]=phi_w1[tid*2+1]; }
  else if (tid<H+PP) epss[tid-H]=pe_eps[tid-H];
  __syncthreads();

  // phase 1: s_pre[r][h] = sum_p relu(ev*wa + el*wb) -> bufA (bf16)
  { int rr=tid>>2, seg=tid&3;
    int node=node0+rr; if (node>=NN) node=NN-1;
    float ev[PP], el[PP];
    const float4* evp=(const float4*)(eigvecs+(size_t)node*PP);
    const float4* elp=(const float4*)(eigvals+(size_t)node*PP);
    #pragma unroll
    for (int q=0;q<4;q++){
      float4 a=evp[q], b=elp[q];
      ev[q*4+0]=a.x; ev[q*4+1]=a.y; ev[q*4+2]=a.z; ev[q*4+3]=a.w;
      el[q*4+0]=b.x; el[q*4+1]=b.y; el[q*4+2]=b.z; el[q*4+3]=b.w;
    }
    #pragma unroll
    for (int p=0;p<PP;p++){
      float a=ev[p]; if (isnan(a)) a=0.f;
      float b=el[p]+epss[p]; if (isnan(b)) b=0.f;
      ev[p]=a; el[p]=b;
    }
    for (int j=0;j<32;j++){
      int h=seg*32+j;
      float wa=was[h], wb=wbs[h];
      float acc=0.f;
      #pragma unroll
      for (int p=0;p<PP;p++) acc+=fmaxf(ev[p]*wa+el[p]*wb,0.f);
      bufA[rr*S1+h]=f2b(acc);
    }
  }
  __syncthreads();
  // phase 2: t = s_pre @ phi_w2^T -> bufB
  pe_gemm(bufA, wpw2, nullptr, bufB, false, wid, l15, l4);
  __syncthreads();
  // phase 3: u = relu(t @ rho_w1^T + b1) -> bufA
  pe_gemm(bufB, wrw1, rho_b1, bufA, true, wid, l15, l4);
  __syncthreads();
  // phase 4: pe = u @ rho_w2^T + b2; tokens[node,0,:] += pe
  { bf16x8 a[4];
    #pragma unroll
    for (int kk=0;kk<4;kk++)
      a[kk]=*(const bf16x8*)(bufA + (wid*16+l15)*S1 + kk*32 + l4*8);
    #pragma unroll
    for (int nt=0;nt<8;nt++){
      int n=nt*16+l15;
      f32x4 c={0.f,0.f,0.f,0.f};
      #pragma unroll
      for (int kk=0;kk<4;kk++){
        bf16x8 bb=*(const bf16x8*)(wrw2 + (size_t)n*H + kk*32 + l4*8);
        c=__builtin_amdgcn_mfma_f32_16x16x32_bf16(a[kk],bb,c,0,0,0);
      }
      float bv=rho_b2[n];
      int rb=wid*16+l4*4;
      #pragma unroll
      for (int reg=0;reg<4;reg++){
        int node=node0+rb+reg;
        if (node<NN) tokens[(size_t)node*4*H + n] += c[reg]+bv;
      }
    }
  }
}

// ---- in-register LN for a wave's 16-row stripe (fp32), write bf16 to hb
__device__ __forceinline__ void ln_block(const float (&tk)[8][4], ushort* hb,
                                         const float* g, const float* bta,
                                         int rowb, int l15){
  float gv[8], bv[8];
  #pragma unroll
  for (int nt=0;nt<8;nt++){ gv[nt]=g[nt*16+l15]; bv[nt]=bta[nt*16+l15]; }
  #pragma unroll
  for (int reg=0;reg<4;reg++){
    float s=0.f,q=0.f;
    #pragma unroll
    for (int nt=0;nt<8;nt++){ float v=tk[nt][reg]; s+=v; q+=v*v; }
    #pragma unroll
    for (int m=1;m<16;m<<=1){ s+=__shfl_xor(s,m); q+=__shfl_xor(q,m); }
    float mean=s*(1.f/128.f);
    float rs=rsqrtf(q*(1.f/128.f)-mean*mean+1e-5f);
    int row=rowb+reg;
    #pragma unroll
    for (int nt=0;nt<8;nt++){
      float hv=(tk[nt][reg]-mean)*rs*gv[nt]+bv[nt];
      hb[row*S1 + nt*16+l15]=f2b(hv);
    }
  }
}

// ---- fused MFMA transformer (2 layers) + head. 32 nodes (128 token-rows)/block.
__global__ __launch_bounds__(512,2) void xform2_kernel(
    const float* __restrict__ tokens, const float* __restrict__ hop_emb,
    const ushort* __restrict__ wqkv, const float* __restrict__ qkv_b,
    const ushort* __restrict__ wout, const float* __restrict__ out_b,
    const float* __restrict__ ln1_g, const float* __restrict__ ln1_b,
    const float* __restrict__ ln2_g, const float* __restrict__ ln2_b,
    const ushort* __restrict__ wff1, const float* __restrict__ ff1_b,
    const ushort* __restrict__ wff2, const float* __restrict__ ff2_b,
    const float* __restrict__ fin_g, const float* __restrict__ fin_b,
    const ushort* __restrict__ hw1b, const float* __restrict__ hb1,
    const float* __restrict__ hlng, const float* __restrict__ hlnb,
    const ushort* __restrict__ hw2b, const float* __restrict__ hb2,
    float* __restrict__ out){
  __shared__ __align__(16) ushort hlb[128*S1];    // 34816 B : A-operand staging
  __shared__ __align__(16) ushort qkvb[128*S2];   // 100352 B: QKV out / FF chunk+Wstage
  __shared__ float red_s[32*8], red_q[32*8], stat_m[32], stat_r[32];
  ushort* chunkA = qkvb;              // [128][S1] FF1 chunk output
  ushort* wstage = qkvb + 128*S1;     // [128][S1] FF2 weight slice

  const int tid=threadIdx.x;
  const int wid=tid>>6;
  const int l=tid&63, l15=l&15, l4=(l>>4)&3;
  const int node0=blockIdx.x*32;
  const int rowb=wid*16 + l4*4;

  // load residual + hop_emb into registers
  float tokacc[8][4];
  const float* tg=tokens + ((size_t)node0*4 + rowb)*H;
  #pragma unroll
  for (int nt=0;nt<8;nt++){
    int col=nt*16+l15;
    #pragma unroll
    for (int reg=0;reg<4;reg++)
      tokacc[nt][reg]=tg[reg*H+col] + hop_emb[reg*H+col];
  }

  for (int ll=0;ll<2;ll++){
    // LN1 -> hlb (bf16)
    ln_block(tokacc, hlb, ln1_g+ll*H, ln1_b+ll*H, rowb, l15);
    __syncthreads();

    // QKV GEMM: C[128x384] = hlb @ Wqkv^T ; wave w does Ntiles {w, w+8, w+16}
    { const ushort* Wl=wqkv + (size_t)ll*384*H;
      bf16x8 bq[3][4]; float bias[3]; int ncol[3];
      #pragma unroll
      for (int j=0;j<3;j++){
        int n=(wid+j*8)*16+l15; ncol[j]=n;
        bias[j]=qkv_b[ll*384+n];
        #pragma unroll
        for (int kk=0;kk<4;kk++)
          bq[j][kk]=*(const bf16x8*)(Wl + (size_t)n*H + kk*32 + l4*8);
      }
      for (int mt=0;mt<8;mt++){
        f32x4 c0={0.f,0.f,0.f,0.f}, c1={0.f,0.f,0.f,0.f}, c2={0.f,0.f,0.f,0.f};
        #pragma unroll
        for (int kk=0;kk<4;kk++){
          bf16x8 a=*(const bf16x8*)(hlb + (mt*16+l15)*S1 + kk*32 + l4*8);
          c0=__builtin_amdgcn_mfma_f32_16x16x32_bf16(a,bq[0][kk],c0,0,0,0);
          c1=__builtin_amdgcn_mfma_f32_16x16x32_bf16(a,bq[1][kk],c1,0,0,0);
          c2=__builtin_amdgcn_mfma_f32_16x16x32_bf16(a,bq[2][kk],c2,0,0,0);
        }
        int rb=mt*16+l4*4;
        #pragma unroll
        for (int reg=0;reg<4;reg++){
          qkvb[(rb+reg)*S2+ncol[0]]=f2b(c0[reg]+bias[0]);
          qkvb[(rb+reg)*S2+ncol[1]]=f2b(c1[reg]+bias[1]);
          qkvb[(rb+reg)*S2+ncol[2]]=f2b(c2[reg]+bias[2]);
        }
      }
    }
    __syncthreads();

    // attention: wave w -> nodes w*4..w*4+3 (its own stripe rows), o -> hlb
    for (int p=0;p<8;p++){
      int idx=p*4+l4;              // 0..31 = nodeLocal(2b)<<3 | head(3b)
      int nloc=idx>>3, hh=idx&7;
      int r0=wid*16+nloc*4;
      int cq=hh*16+l15;
      float qv[4],kv[4],vv[4];
      #pragma unroll
      for (int s4=0;s4<4;s4++){
        qv[s4]=b2f(qkvb[(r0+s4)*S2+cq]);
        kv[s4]=b2f(qkvb[(r0+s4)*S2+128+cq]);
        vv[s4]=b2f(qkvb[(r0+s4)*S2+256+cq]);
      }
      float sc[4][4];
      #pragma unroll
      for (int s4=0;s4<4;s4++){
        #pragma unroll
        for (int u=0;u<4;u++){
          float pp=qv[s4]*kv[u];
          pp+=__shfl_xor(pp,1); pp+=__shfl_xor(pp,2);
          pp+=__shfl_xor(pp,4); pp+=__shfl_xor(pp,8);
          sc[s4][u]=pp*0.25f;
        }
      }
      #pragma unroll
      for (int s4=0;s4<4;s4++){
        float m=fmaxf(fmaxf(sc[s4][0],sc[s4][1]),fmaxf(sc[s4][2],sc[s4][3]));
        float e0=__expf(sc[s4][0]-m), e1=__expf(sc[s4][1]-m),
              e2=__expf(sc[s4][2]-m), e3=__expf(sc[s4][3]-m);
        float inv=1.f/(e0+e1+e2+e3);
        float o=(e0*vv[0]+e1*vv[1]+e2*vv[2]+e3*vv[3])*inv;
        hlb[(r0+s4)*S1+cq]=f2b(o);
      }
    }
    __syncthreads();

    // out-proj: wave-local Mtile=w; tokacc += o @ Wout^T + b
    { const ushort* Wl=wout + (size_t)ll*H*H;
      bf16x8 a[4];
      #pragma unroll
      for (int kk=0;kk<4;kk++)
        a[kk]=*(const bf16x8*)(hlb + (wid*16+l15)*S1 + kk*32 + l4*8);
      #pragma unroll
      for (int nt=0;nt<8;nt++){
        int n=nt*16+l15;
        f32x4 c={0.f,0.f,0.f,0.f};
        #pragma unroll
        for (int kk=0;kk<4;kk++){
          bf16x8 bb=*(const bf16x8*)(Wl + (size_t)n*H + kk*32 + l4*8);
          c=__builtin_amdgcn_mfma_f32_16x16x32_bf16(a[kk],bb,c,0,0,0);
        }
        float bias=out_b[ll*H+n];
        #pragma unroll
        for (int reg=0;reg<4;reg++) tokacc[nt][reg]+=c[reg]+bias;
      }
    }

    // LN2 -> hlb
    ln_block(tokacc, hlb, ln2_g+ll*H, ln2_b+ll*H, rowb, l15);
    __syncthreads();

    // FF: 4 K-chunks of 128; FF1 -> chunkA (relu,bf16); FF2 accumulates fac
    { const ushort* w1l=wff1 + (size_t)ll*512*H;
      const ushort* w2l=wff2 + (size_t)ll*H*512;
      f32x4 fac[8];
      #pragma unroll
      for (int nt=0;nt<8;nt++) fac[nt]=(f32x4){0.f,0.f,0.f,0.f};
      for (int c0=0;c0<4;c0++){
        // cooperative stage of Wff2[:, c0*128 : c0*128+128) into wstage
        { int rr=tid>>2, seg=tid&3;
          #pragma unroll
          for (int i=0;i<4;i++)
            *(bf16x8*)(wstage + rr*S1 + seg*32 + i*8) =
              *(const bf16x8*)(w2l + (size_t)rr*512 + c0*128 + seg*32 + i*8);
        }
        // FF1: wave w computes global Ntile c0*8+w -> chunkA cols w*16..
        { int n=(c0*8+wid)*16+l15;
          bf16x8 b1[4];
          #pragma unroll
          for (int kk=0;kk<4;kk++)
            b1[kk]=*(const bf16x8*)(w1l + (size_t)n*H + kk*32 + l4*8);
          float bias1=ff1_b[ll*512+n];
          for (int mt=0;mt<8;mt++){
            f32x4 c={0.f,0.f,0.f,0.f};
            #pragma unroll
            for (int kk=0;kk<4;kk++){
              bf16x8 a=*(const bf16x8*)(hlb + (mt*16+l15)*S1 + kk*32 + l4*8);
              c=__builtin_amdgcn_mfma_f32_16x16x32_bf16(a,b1[kk],c,0,0,0);
            }
            int rb=mt*16+l4*4;
            #pragma unroll
            for (int reg=0;reg<4;reg++)
              chunkA[(rb+reg)*S1 + wid*16+l15]=f2b(fmaxf(c[reg]+bias1,0.f));
          }
        }
        __syncthreads();
        // FF2 partial: A = chunkA wave-local stripe; B = wstage
        { bf16x8 a2[4];
          #pragma unroll
          for (int kk=0;kk<4;kk++)
            a2[kk]=*(const bf16x8*)(chunkA + (wid*16+l15)*S1 + kk*32 + l4*8);
          #pragma unroll
          for (int nt=0;nt<8;nt++){
            int n2=nt*16+l15;
            #pragma unroll
            for (int kk=0;kk<4;kk++){
              bf16x8 bb=*(const bf16x8*)(wstage + n2*S1 + kk*32 + l4*8);
              fac[nt]=__builtin_amdgcn_mfma_f32_16x16x32_bf16(a2[kk],bb,fac[nt],0,0,0);
            }
          }
        }
        __syncthreads();
      }
      #pragma unroll
      for (int nt=0;nt<8;nt++){
        float b2v=ff2_b[ll*H + nt*16+l15];
        #pragma unroll
        for (int reg=0;reg<4;reg++) tokacc[nt][reg]+=fac[nt][reg]+b2v;
      }
    }
  }

  // ---- final LN on token-0 rows (reg==0 slots), compact to hlb rows 0..31
  { float s=0.f,q=0.f;
    #pragma unroll
    for (int nt=0;nt<8;nt++){ float v=tokacc[nt][0]; s+=v; q+=v*v; }
    #pragma unroll
    for (int m=1;m<16;m<<=1){ s+=__shfl_xor(s,m); q+=__shfl_xor(q,m); }
    float mean=s*(1.f/128.f);
    float rs=rsqrtf(q*(1.f/128.f)-mean*mean+1e-5f);
    int ci=wid*4+l4;       // compact node-local row 0..31
    #pragma unroll
    for (int nt=0;nt<8;nt++){
      int col=nt*16+l15;
      float hv=(tokacc[nt][0]-mean)*rs*fin_g[col]+fin_b[col];
      hlb[ci*S1+col]=f2b(hv);
    }
  }
  __syncthreads();

  // ---- head GEMM1 [32x128]@hw1^T + gelu
  float gel[2][4];
  { int n=wid*16+l15;
    bf16x8 bh[4];
    #pragma unroll
    for (int kk=0;kk<4;kk++)
      bh[kk]=*(const bf16x8*)(hw1b + (size_t)n*H + kk*32 + l4*8);
    float hb1v=hb1[n];
    #pragma unroll
    for (int mt=0;mt<2;mt++){
      f32x4 c={0.f,0.f,0.f,0.f};
      #pragma unroll
      for (int kk=0;kk<4;kk++){
        bf16x8 a=*(const bf16x8*)(hlb + (mt*16+l15)*S1 + kk*32 + l4*8);
        c=__builtin_amdgcn_mfma_f32_16x16x32_bf16(a,bh[kk],c,0,0,0);
      }
      #pragma unroll
      for (int reg=0;reg<4;reg++){
        float xx=c[reg]+hb1v;
        gel[mt][reg]=0.5f*xx*(1.f+erff(xx*0.70710678118654752f));
      }
    }
  }
  // ---- head LN (cross-wave)
  #pragma unroll
  for (int mt=0;mt<2;mt++){
    #pragma unroll
    for (int reg=0;reg<4;reg++){
      float v=gel[mt][reg], sv=v, qv=v*v;
      #pragma unroll
      for (int m=1;m<16;m<<=1){ sv+=__shfl_xor(sv,m); qv+=__shfl_xor(qv,m); }
      if (l15==0){ int r32=mt*16+l4*4+reg; red_s[r32*8+wid]=sv; red_q[r32*8+wid]=qv; }
    }
  }
  __syncthreads();
  if (tid<32){
    float ss=0.f,qs=0.f;
    #pragma unroll
    for (int w=0;w<8;w++){ ss+=red_s[tid*8+w]; qs+=red_q[tid*8+w]; }
    float mm=ss*(1.f/128.f);
    stat_m[tid]=mm;
    stat_r[tid]=rsqrtf(qs*(1.f/128.f)-mm*mm+1e-5f);
  }
  __syncthreads();
  { int n=wid*16+l15;
    float hg=hlng[n], hbv=hlnb[n];
    #pragma unroll
    for (int mt=0;mt<2;mt++){
      #pragma unroll
      for (int reg=0;reg<4;reg++){
        int r32=mt*16+l4*4+reg;
        float z=(gel[mt][reg]-stat_m[r32])*stat_r[r32]*hg+hbv;
        hlb[r32*S1+n]=f2b(z);
      }
    }
  }
  __syncthreads();

  // ---- head GEMM2 [32x128] @ hw2^T -> out (waves 0,1)
  if (wid<2){
    int mt=wid;
    bool valid=l15<10;
    bf16x8 b2[4];
    #pragma unroll
    for (int kk=0;kk<4;kk++){
      if (valid) b2[kk]=*(const bf16x8*)(hw2b + (size_t)l15*H + kk*32 + l4*8);
      else { bf16x8 z; for (int t=0;t<8;t++) z[t]=0; b2[kk]=z; }
    }
    f32x4 c={0.f,0.f,0.f,0.f};
    #pragma unroll
    for (int kk=0;kk<4;kk++){
      bf16x8 a=*(const bf16x8*)(hlb + (mt*16+l15)*S1 + kk*32 + l4*8);
      c=__builtin_amdgcn_mfma_f32_16x16x32_bf16(a,b2[kk],c,0,0,0);
    }
    if (valid){
      float bb2=hb2[l15];
      #pragma unroll
      for (int reg=0;reg<4;reg++){
        int i=mt*16+l4*4+reg;
        out[((size_t)node0+i)*10 + l15]=c[reg]+bb2;
      }
    }
  }
}

extern "C" void kernel_launch(void* const* d_in, const int* in_sizes, int n_in,
                              void* d_out, int out_size, void* d_ws, size_t ws_size,
                              hipStream_t stream){
  const float* x       =(const float*)d_in[0];
  const int*   ei      =(const int*)  d_in[1];
  const float* eigvecs =(const float*)d_in[2];
  const float* eigvals =(const float*)d_in[3];
  const float* enc_w   =(const float*)d_in[4];
  const float* enc_b   =(const float*)d_in[5];
  const float* in_ln_g =(const float*)d_in[6];
  const float* in_ln_b =(const float*)d_in[7];
  const float* pe_phi_w1=(const float*)d_in[8];
  const float* pe_phi_w2=(const float*)d_in[9];
  const float* pe_rho_w1=(const float*)d_in[10];
  const float* pe_rho_b1=(const float*)d_in[11];
  const float* pe_rho_w2=(const float*)d_in[12];
  const float* pe_rho_b2=(const float*)d_in[13];
  const float* pe_eps  =(const float*)d_in[14];
  const float* hop_emb =(const float*)d_in[15];
  const float* qkv_w   =(const float*)d_in[16];
  const float* qkv_b   =(const float*)d_in[17];
  const float* out_w   =(const float*)d_in[18];
  const float* out_b   =(const float*)d_in[19];
  const float* ln1_g   =(const float*)d_in[20];
  const float* ln1_b   =(const float*)d_in[21];
  const float* ln2_g   =(const float*)d_in[22];
  const float* ln2_b   =(const float*)d_in[23];
  const float* ff1_w   =(const float*)d_in[24];
  const float* ff1_b   =(const float*)d_in[25];
  const float* ff2_w   =(const float*)d_in[26];
  const float* ff2_b   =(const float*)d_in[27];
  const float* fin_g   =(const float*)d_in[28];
  const float* fin_b   =(const float*)d_in[29];
  const float* hw1     =(const float*)d_in[30];
  const float* hb1     =(const float*)d_in[31];
  const float* hlg     =(const float*)d_in[32];
  const float* hlb_    =(const float*)d_in[33];
  const float* hw2     =(const float*)d_in[34];
  const float* hb2     =(const float*)d_in[35];

  char* ws=(char*)d_ws;
  size_t off=0;
  auto alloc=[&](size_t bytes)->void*{
    void* p=ws+off;
    off+=(bytes+255)&~(size_t)255;
    return p;
  };
  float* tokens =(float*)alloc((size_t)NN*4*H*sizeof(float));   // 204.8 MB
  float* deg    =(float*)alloc((size_t)NN*sizeof(float));       // becomes dinv
  int*   counts =(int*)  alloc((size_t)NN*sizeof(int));
  int*   row_ptr=(int*)  alloc((size_t)(NN+1)*sizeof(int));
  int*   cursor =(int*)  alloc((size_t)NN*sizeof(int));
  int*   cs_col =(int*)  alloc((size_t)EE*sizeof(int));
  float* cs_w   =(float*)alloc((size_t)EE*sizeof(float));
  int*   flag   =(int*)  alloc(256);
  // bf16 weight copies
  ushort* wqkvb =(ushort*)alloc((size_t)2*384*H*sizeof(ushort));
  ushort* woutb =(ushort*)alloc((size_t)2*H*H*sizeof(ushort));
  ushort* wff1b =(ushort*)alloc((size_t)2*512*H*sizeof(ushort));
  ushort* wff2b =(ushort*)alloc((size_t)2*H*512*sizeof(ushort));
  ushort* hw1b  =(ushort*)alloc((size_t)H*H*sizeof(ushort));
  ushort* hw2b  =(ushort*)alloc((size_t)10*H*sizeof(ushort));
  ushort* wpw2b =(ushort*)alloc((size_t)H*H*sizeof(ushort));
  ushort* wrw1b =(ushort*)alloc((size_t)H*H*sizeof(ushort));
  ushort* wrw2b =(ushort*)alloc((size_t)H*H*sizeof(ushort));
  if (off>ws_size) return; // workspace insufficient

  hipMemsetAsync(deg,0,(size_t)NN*sizeof(float),stream);
  hipMemsetAsync(counts,0,(size_t)NN*sizeof(int),stream);
  detect_kernel<<<1,256,0,stream>>>(ei,flag);
  // weight conversions
  cvtw_kernel<<<(2*384*H+255)/256,256,0,stream>>>(qkv_w,wqkvb,2*384*H);
  cvtw_kernel<<<(2*H*H+255)/256,256,0,stream>>>(out_w,woutb,2*H*H);
  cvtw_kernel<<<(2*512*H+255)/256,256,0,stream>>>(ff1_w,wff1b,2*512*H);
  cvtw_kernel<<<(2*H*512+255)/256,256,0,stream>>>(ff2_w,wff2b,2*H*512);
  cvtw_kernel<<<(H*H+255)/256,256,0,stream>>>(hw1,hw1b,H*H);
  cvtw_kernel<<<(10*H+255)/256,256,0,stream>>>(hw2,hw2b,10*H);
  cvtw_kernel<<<(H*H+255)/256,256,0,stream>>>(pe_phi_w2,wpw2b,H*H);
  cvtw_kernel<<<(H*H+255)/256,256,0,stream>>>(pe_rho_w1,wrw1b,H*H);
  cvtw_kernel<<<(H*H+255)/256,256,0,stream>>>(pe_rho_w2,wrw2b,H*H);

  enc_kernel<<<NN/2,256,0,stream>>>(x,enc_w,enc_b,in_ln_g,in_ln_b,tokens);
  hist_kernel<<<(EE+255)/256,256,0,stream>>>(ei,flag,deg,counts);
  dinv_kernel<<<(NN+255)/256,256,0,stream>>>(deg);
  scan_kernel<<<1,1024,0,stream>>>(counts,row_ptr,cursor);
  scatter_kernel<<<(EE+255)/256,256,0,stream>>>(ei,flag,cursor,deg,cs_col,cs_w);
  for (int k=0;k<3;k++)
    spmm_kernel<<<NN/2,256,0,stream>>>(tokens,row_ptr,cs_col,cs_w,k);
  pe2_kernel<<<(NN+127)/128,512,0,stream>>>(eigvecs,eigvals,pe_phi_w1,pe_eps,
                                            wpw2b,wrw1b,pe_rho_b1,wrw2b,pe_rho_b2,
                                            tokens);
  xform2_kernel<<<NN/32,512,0,stream>>>(tokens,hop_emb,
                                        wqkvb,qkv_b,woutb,out_b,
                                        ln1_g,ln1_b,ln2_g,ln2_b,
                                        wff1b,ff1_b,wff2b,ff2_b,
                                        fin_g,fin_b,hw1b,hb1,hlg,hlb_,hw2b,hb2,
                                        (float*)d_out);
}

// Round 5
// 2855.500 us; speedup vs baseline: 8.2708x; 1.1400x over previous
//
#include <hip/hip_runtime.h>
#include <cmath>

#define NN 100000
#define EE 1600000
#define H 128
#define PP 16
#define S1 136   // LDS A-stride (halfwords)

typedef __attribute__((ext_vector_type(8))) short bf16x8;
typedef __attribute__((ext_vector_type(4))) float f32x4;

__device__ __forceinline__ float wred64(float v){
  v += __shfl_xor(v,32); v += __shfl_xor(v,16); v += __shfl_xor(v,8);
  v += __shfl_xor(v,4);  v += __shfl_xor(v,2);  v += __shfl_xor(v,1);
  return v;
}
__device__ __forceinline__ ushort f2b(float f){
  union{float f; unsigned u;} x; x.f=f;
  unsigned r=(x.u + 0x7fffu + ((x.u>>16)&1u))>>16;
  return (ushort)r;
}
__device__ __forceinline__ unsigned pack2(float a, float b){
  return (unsigned)f2b(a) | ((unsigned)f2b(b)<<16);
}

// ---- weight fp32 -> bf16 conversion
__global__ void cvtw_kernel(const float* __restrict__ src, ushort* __restrict__ dst, int n){
  int i=blockIdx.x*256+threadIdx.x;
  if (i<n) dst[i]=f2b(src[i]);
}

// ---- edge_index dtype detect: flag=1 if int64 (odd words all zero), else 0
__global__ void detect_kernel(const int* __restrict__ ei, int* __restrict__ flag){
  __shared__ int nz;
  if (threadIdx.x==0) nz=0;
  __syncthreads();
  for (int i=threadIdx.x; i<2048; i+=256){
    if (ei[2*i+1]!=0) nz=1;
  }
  __syncthreads();
  if (threadIdx.x==0) flag[0] = nz ? 0 : 1;
}

// ---- MFMA encoder: tokens[n,0,:] = LN(x @ enc_w^T + enc_b); 128 nodes/block
__global__ __launch_bounds__(512) void enc2_kernel(
    const float* __restrict__ x, const ushort* __restrict__ wenc,
    const float* __restrict__ enc_b,
    const float* __restrict__ g, const float* __restrict__ bb,
    float* __restrict__ tokens){
  __shared__ __align__(16) ushort bufA[128*S1];
  const int tid=threadIdx.x;
  const int wid=tid>>6;
  const int l=tid&63, l15=l&15, l4=(l>>4)&3;
  const int node0=blockIdx.x*128;
  const int rowb=wid*16 + l4*4;

  // stage x rows fp32 -> bf16
  { int rr=tid>>2, seg=tid&3;
    int node=node0+rr; if (node>=NN) node=NN-1;
    const float4* xr=(const float4*)(x+(size_t)node*H+seg*32);
    #pragma unroll
    for (int i=0;i<8;i++){
      float4 v=xr[i];
      *(unsigned*)(bufA + rr*S1 + seg*32 + i*4)   = pack2(v.x,v.y);
      *(unsigned*)(bufA + rr*S1 + seg*32 + i*4+2) = pack2(v.z,v.w);
    }
  }
  __syncthreads();

  // wave-local GEMM rows [wid*16,wid*16+16) x all 128 cols
  bf16x8 a[4];
  #pragma unroll
  for (int kk=0;kk<4;kk++)
    a[kk]=*(const bf16x8*)(bufA + (wid*16+l15)*S1 + kk*32 + l4*8);
  float acc[8][4];
  #pragma unroll
  for (int nt=0;nt<8;nt++){
    int n=nt*16+l15;
    f32x4 c={0.f,0.f,0.f,0.f};
    #pragma unroll
    for (int kk=0;kk<4;kk++){
      bf16x8 bbf=*(const bf16x8*)(wenc + (size_t)n*H + kk*32 + l4*8);
      c=__builtin_amdgcn_mfma_f32_16x16x32_bf16(a[kk],bbf,c,0,0,0);
    }
    float bv=enc_b[n];
    #pragma unroll
    for (int reg=0;reg<4;reg++) acc[nt][reg]=c[reg]+bv;
  }
  // in-register LN per row, write fp32 tokens[:,0,:]
  float gv[8], bvv[8];
  #pragma unroll
  for (int nt=0;nt<8;nt++){ gv[nt]=g[nt*16+l15]; bvv[nt]=bb[nt*16+l15]; }
  #pragma unroll
  for (int reg=0;reg<4;reg++){
    float s=0.f,q=0.f;
    #pragma unroll
    for (int nt=0;nt<8;nt++){ float v=acc[nt][reg]; s+=v; q+=v*v; }
    #pragma unroll
    for (int m=1;m<16;m<<=1){ s+=__shfl_xor(s,m); q+=__shfl_xor(q,m); }
    float mean=s*(1.f/128.f);
    float rs=rsqrtf(q*(1.f/128.f)-mean*mean+1e-5f);
    int node=node0+rowb+reg;
    if (node<NN){
      #pragma unroll
      for (int nt=0;nt<8;nt++)
        tokens[(size_t)node*4*H + nt*16+l15]=(acc[nt][reg]-mean)*rs*gv[nt]+bvv[nt];
    }
  }
}

// ---- histograms: deg over col (float), counts over row (int)
__global__ void hist_kernel(const int* __restrict__ ei, const int* __restrict__ flag,
                            float* __restrict__ deg, int* __restrict__ counts){
  int f=flag[0];
  int e=blockIdx.x*256+threadIdx.x;
  if (e>=EE) return;
  int rw=ei[(size_t)e<<f];
  int cl=ei[((size_t)EE+e)<<f];
  atomicAdd(&counts[rw],1);
  atomicAdd(&deg[cl],1.0f);
}

__global__ void dinv_kernel(float* __restrict__ deg){
  int i=blockIdx.x*256+threadIdx.x;
  if (i<NN) deg[i]=rsqrtf(fmaxf(deg[i],1.0f));
}

// ---- single-block exclusive scan of counts -> row_ptr, cursor
__global__ __launch_bounds__(1024) void scan_kernel(const int* __restrict__ counts,
                                                    int* __restrict__ row_ptr, int* __restrict__ cursor){
  __shared__ int wsum_s[16];
  __shared__ int carry_s;
  int tid=threadIdx.x, lane=tid&63, w=tid>>6;
  if (tid==0) carry_s=0;
  __syncthreads();
  for (int base=0; base<NN; base+=1024){
    int i=base+tid;
    int v=(i<NN)?counts[i]:0;
    int x=v;
    for (int off=1; off<64; off<<=1){
      int t=__shfl_up(x,off);
      if (lane>=off) x+=t;
    }
    if (lane==63) wsum_s[w]=x;
    __syncthreads();
    int woff=0;
    #pragma unroll
    for (int ww=0; ww<16; ww++) if (ww<w) woff+=wsum_s[ww];
    int carry=carry_s;
    int excl=carry+woff+x-v;
    if (i<NN){ row_ptr[i]=excl; cursor[i]=excl; }
    __syncthreads();
    if (tid==1023) carry_s = carry + woff + x;
    __syncthreads();
  }
  if (tid==0) row_ptr[NN]=carry_s;
}

// ---- scatter edges into CSR (col + weight)
__global__ void scatter_kernel(const int* __restrict__ ei, const int* __restrict__ flag,
                               int* __restrict__ cursor, const float* __restrict__ dinv,
                               int* __restrict__ cs_col, float* __restrict__ cs_w){
  int f=flag[0];
  int e=blockIdx.x*256+threadIdx.x;
  if (e>=EE) return;
  int rw=ei[(size_t)e<<f];
  int cl=ei[((size_t)EE+e)<<f];
  int pos=atomicAdd(&cursor[rw],1);
  cs_col[pos]=cl;
  cs_w[pos]=dinv[rw]*dinv[cl];
}

// ---- SpMM hop: tokens[:,k+1,:] = A_norm @ tokens[:,k,:]
__global__ __launch_bounds__(256) void spmm_kernel(float* __restrict__ tokens,
    const int* __restrict__ row_ptr, const int* __restrict__ cs_col,
    const float* __restrict__ cs_w, int k){
  int tid=threadIdx.x;
  int n=blockIdx.x*2+(tid>>7);
  int t=tid&127;
  int beg=row_ptr[n], end=row_ptr[n+1];
  float acc=0.f;
  const float* src=tokens+(size_t)k*H+t;
  for (int j=beg;j<end;j++){
    acc += cs_w[j]*src[(size_t)cs_col[j]*(4*H)];
  }
  tokens[((size_t)n*4+k+1)*H+t]=acc;
}

// ---- one 128x128 @ 128x128^T MFMA step (wave-local 16-row stripe)
__device__ __forceinline__ void pe_gemm(const ushort* Ain, const ushort* __restrict__ W,
                                        const float* __restrict__ bias, ushort* Aout,
                                        bool dorelu, int wid, int l15, int l4){
  bf16x8 a[4];
  #pragma unroll
  for (int kk=0;kk<4;kk++)
    a[kk]=*(const bf16x8*)(Ain + (wid*16+l15)*S1 + kk*32 + l4*8);
  #pragma unroll
  for (int nt=0;nt<8;nt++){
    int n=nt*16+l15;
    f32x4 c={0.f,0.f,0.f,0.f};
    #pragma unroll
    for (int kk=0;kk<4;kk++){
      bf16x8 bb=*(const bf16x8*)(W + (size_t)n*H + kk*32 + l4*8);
      c=__builtin_amdgcn_mfma_f32_16x16x32_bf16(a[kk],bb,c,0,0,0);
    }
    float bv=bias?bias[n]:0.f;
    int rb=wid*16+l4*4;
    #pragma unroll
    for (int reg=0;reg<4;reg++){
      float v=c[reg]+bv;
      if (dorelu) v=fmaxf(v,0.f);
      Aout[(rb+reg)*S1+n]=f2b(v);
    }
  }
}

// ---- PE via MFMA: 128 nodes/block, 8 waves, tokens[:,0,:] += rho(...)
__global__ __launch_bounds__(512) void pe2_kernel(
    const float* __restrict__ eigvecs, const float* __restrict__ eigvals,
    const float* __restrict__ phi_w1, const float* __restrict__ pe_eps,
    const ushort* __restrict__ wpw2,
    const ushort* __restrict__ wrw1, const float* __restrict__ rho_b1,
    const ushort* __restrict__ wrw2, const float* __restrict__ rho_b2,
    float* __restrict__ tokens){
  __shared__ __align__(16) ushort bufA[128*S1];
  __shared__ __align__(16) ushort bufB[128*S1];
  __shared__ float was[H], wbs[H], epss[PP];
  const int tid=threadIdx.x;
  const int wid=tid>>6;
  const int l=tid&63, l15=l&15, l4=(l>>4)&3;
  const int node0=blockIdx.x*128;

  if (tid<H){ was[tid]=phi_w1[tid*2]; wbs[tid]=phi_w1[tid*2+1]; }
  else if (tid<H+PP) epss[tid-H]=pe_eps[tid-H];
  __syncthreads();

  // phase 1: s_pre[r][h] = sum_p relu(ev*wa + el*wb) -> bufA (bf16)
  { int rr=tid>>2, seg=tid&3;
    int node=node0+rr; if (node>=NN) node=NN-1;
    float ev[PP], el[PP];
    const float4* evp=(const float4*)(eigvecs+(size_t)node*PP);
    const float4* elp=(const float4*)(eigvals+(size_t)node*PP);
    #pragma unroll
    for (int q=0;q<4;q++){
      float4 a=evp[q], b=elp[q];
      ev[q*4+0]=a.x; ev[q*4+1]=a.y; ev[q*4+2]=a.z; ev[q*4+3]=a.w;
      el[q*4+0]=b.x; el[q*4+1]=b.y; el[q*4+2]=b.z; el[q*4+3]=b.w;
    }
    #pragma unroll
    for (int p=0;p<PP;p++){
      float a=ev[p]; if (isnan(a)) a=0.f;
      float b=el[p]+epss[p]; if (isnan(b)) b=0.f;
      ev[p]=a; el[p]=b;
    }
    for (int j=0;j<32;j++){
      int h=seg*32+j;
      float wa=was[h], wb=wbs[h];
      float acc=0.f;
      #pragma unroll
      for (int p=0;p<PP;p++) acc+=fmaxf(ev[p]*wa+el[p]*wb,0.f);
      bufA[rr*S1+h]=f2b(acc);
    }
  }
  __syncthreads();
  pe_gemm(bufA, wpw2, nullptr, bufB, false, wid, l15, l4);
  __syncthreads();
  pe_gemm(bufB, wrw1, rho_b1, bufA, true, wid, l15, l4);
  __syncthreads();
  // phase 4: pe = u @ rho_w2^T + b2; tokens[node,0,:] += pe
  { bf16x8 a[4];
    #pragma unroll
    for (int kk=0;kk<4;kk++)
      a[kk]=*(const bf16x8*)(bufA + (wid*16+l15)*S1 + kk*32 + l4*8);
    #pragma unroll
    for (int nt=0;nt<8;nt++){
      int n=nt*16+l15;
      f32x4 c={0.f,0.f,0.f,0.f};
      #pragma unroll
      for (int kk=0;kk<4;kk++){
        bf16x8 bb=*(const bf16x8*)(wrw2 + (size_t)n*H + kk*32 + l4*8);
        c=__builtin_amdgcn_mfma_f32_16x16x32_bf16(a[kk],bb,c,0,0,0);
      }
      float bv=rho_b2[n];
      int rb=wid*16+l4*4;
      #pragma unroll
      for (int reg=0;reg<4;reg++){
        int node=node0+rb+reg;
        if (node<NN) tokens[(size_t)node*4*H + n] += c[reg]+bv;
      }
    }
  }
}

// ---- in-register LN for a wave's 16-row stripe (fp32), write bf16 to hb
__device__ __forceinline__ void ln_block(const float (&tk)[8][4], ushort* hb,
                                         const float* g, const float* bta,
                                         int rowb, int l15){
  float gv[8], bv[8];
  #pragma unroll
  for (int nt=0;nt<8;nt++){ gv[nt]=g[nt*16+l15]; bv[nt]=bta[nt*16+l15]; }
  #pragma unroll
  for (int reg=0;reg<4;reg++){
    float s=0.f,q=0.f;
    #pragma unroll
    for (int nt=0;nt<8;nt++){ float v=tk[nt][reg]; s+=v; q+=v*v; }
    #pragma unroll
    for (int m=1;m<16;m<<=1){ s+=__shfl_xor(s,m); q+=__shfl_xor(q,m); }
    float mean=s*(1.f/128.f);
    float rs=rsqrtf(q*(1.f/128.f)-mean*mean+1e-5f);
    int row=rowb+reg;
    #pragma unroll
    for (int nt=0;nt<8;nt++){
      float hv=(tk[nt][reg]-mean)*rs*gv[nt]+bv[nt];
      hb[row*S1 + nt*16+l15]=f2b(hv);
    }
  }
}

// ---- fused MFMA transformer (2 layers) + head. 32 nodes/block, 8 waves.
// In-register attention: wave w == head w (QKV N-tiles {w,w+8,w+16} are exactly
// Q/K/V cols [w*16,w*16+16)). LDS = hlb + chA = 72 KB -> 2 blocks/CU.
__global__ __launch_bounds__(512,4) void xform3_kernel(
    const float* __restrict__ tokens, const float* __restrict__ hop_emb,
    const ushort* __restrict__ wqkv, const float* __restrict__ qkv_b,
    const ushort* __restrict__ wout, const float* __restrict__ out_b,
    const float* __restrict__ ln1_g, const float* __restrict__ ln1_b,
    const float* __restrict__ ln2_g, const float* __restrict__ ln2_b,
    const ushort* __restrict__ wff1, const float* __restrict__ ff1_b,
    const ushort* __restrict__ wff2, const float* __restrict__ ff2_b,
    const float* __restrict__ fin_g, const float* __restrict__ fin_b,
    const ushort* __restrict__ hw1b, const float* __restrict__ hb1,
    const float* __restrict__ hlng, const float* __restrict__ hlnb,
    const ushort* __restrict__ hw2b, const float* __restrict__ hb2,
    float* __restrict__ out){
  __shared__ __align__(16) ushort hlb[128*S1];   // 34816 B: LN output (A operand)
  __shared__ __align__(16) ushort chA[128*S1];   // 34816 B: attn-o / FF1 chunk
  __shared__ float red_s[32*8], red_q[32*8], stat_m[32], stat_r[32];

  const int tid=threadIdx.x;
  const int wid=tid>>6;
  const int l=tid&63, l15=l&15, l4=(l>>4)&3;
  const int node0=blockIdx.x*32;
  const int rowb=wid*16 + l4*4;

  float tokacc[8][4];
  const float* tg=tokens + ((size_t)node0*4 + rowb)*H;
  #pragma unroll
  for (int nt=0;nt<8;nt++){
    int col=nt*16+l15;
    #pragma unroll
    for (int reg=0;reg<4;reg++)
      tokacc[nt][reg]=tg[reg*H+col] + hop_emb[reg*H+col];
  }

  for (int ll=0;ll<2;ll++){
    // LN1 -> hlb (bf16)
    ln_block(tokacc, hlb, ln1_g+ll*H, ln1_b+ll*H, rowb, l15);
    __syncthreads();

    // fused QKV GEMM + in-register attention; o -> chA
    { const ushort* Wl=wqkv + (size_t)ll*384*H;
      bf16x8 bq[3][4];
      #pragma unroll
      for (int j=0;j<3;j++){
        int n=(wid+j*8)*16+l15;
        #pragma unroll
        for (int kk=0;kk<4;kk++)
          bq[j][kk]=*(const bf16x8*)(Wl + (size_t)n*H + kk*32 + l4*8);
      }
      float bz0=qkv_b[ll*384       + wid*16+l15];
      float bz1=qkv_b[ll*384 + 128 + wid*16+l15];
      float bz2=qkv_b[ll*384 + 256 + wid*16+l15];
      for (int mt=0;mt<8;mt++){
        f32x4 c0={0.f,0.f,0.f,0.f}, c1={0.f,0.f,0.f,0.f}, c2={0.f,0.f,0.f,0.f};
        #pragma unroll
        for (int kk=0;kk<4;kk++){
          bf16x8 a=*(const bf16x8*)(hlb + (mt*16+l15)*S1 + kk*32 + l4*8);
          c0=__builtin_amdgcn_mfma_f32_16x16x32_bf16(a,bq[0][kk],c0,0,0,0);
          c1=__builtin_amdgcn_mfma_f32_16x16x32_bf16(a,bq[1][kk],c1,0,0,0);
          c2=__builtin_amdgcn_mfma_f32_16x16x32_bf16(a,bq[2][kk],c2,0,0,0);
        }
        // lane holds q/k/v[token s] for node mt*4+l4, head wid, dim l15
        float qv[4],kv[4],vv[4];
        #pragma unroll
        for (int s=0;s<4;s++){ qv[s]=c0[s]+bz0; kv[s]=c1[s]+bz1; vv[s]=c2[s]+bz2; }
        float sc[4][4];
        #pragma unroll
        for (int s=0;s<4;s++){
          #pragma unroll
          for (int u=0;u<4;u++){
            float p=qv[s]*kv[u];
            p+=__shfl_xor(p,1); p+=__shfl_xor(p,2);
            p+=__shfl_xor(p,4); p+=__shfl_xor(p,8);
            sc[s][u]=p*0.25f;
          }
        }
        #pragma unroll
        for (int s=0;s<4;s++){
          float m=fmaxf(fmaxf(sc[s][0],sc[s][1]),fmaxf(sc[s][2],sc[s][3]));
          float e0=__expf(sc[s][0]-m), e1=__expf(sc[s][1]-m),
                e2=__expf(sc[s][2]-m), e3=__expf(sc[s][3]-m);
          float inv=1.f/(e0+e1+e2+e3);
          float o=(e0*vv[0]+e1*vv[1]+e2*vv[2]+e3*vv[3])*inv;
          chA[(mt*16+l4*4+s)*S1 + wid*16+l15]=f2b(o);
        }
      }
    }
    __syncthreads();

    // out-proj: tokacc += o @ Wout^T + b (A from chA own stripe)
    { const ushort* Wl=wout + (size_t)ll*H*H;
      bf16x8 a[4];
      #pragma unroll
      for (int kk=0;kk<4;kk++)
        a[kk]=*(const bf16x8*)(chA + (wid*16+l15)*S1 + kk*32 + l4*8);
      #pragma unroll
      for (int nt=0;nt<8;nt++){
        int n=nt*16+l15;
        f32x4 c={0.f,0.f,0.f,0.f};
        #pragma unroll
        for (int kk=0;kk<4;kk++){
          bf16x8 bb=*(const bf16x8*)(Wl + (size_t)n*H + kk*32 + l4*8);
          c=__builtin_amdgcn_mfma_f32_16x16x32_bf16(a[kk],bb,c,0,0,0);
        }
        float bias=out_b[ll*H+n];
        #pragma unroll
        for (int reg=0;reg<4;reg++) tokacc[nt][reg]+=c[reg]+bias;
      }
    }

    // LN2 -> hlb (wave-local rows; hlb reads finished before last barrier)
    ln_block(tokacc, hlb, ln2_g+ll*H, ln2_b+ll*H, rowb, l15);
    __syncthreads();

    // FF: 4 K-chunks of 128; FF1 -> chA (relu); FF2 accumulates (B from global)
    { const ushort* w1l=wff1 + (size_t)ll*512*H;
      const ushort* w2l=wff2 + (size_t)ll*H*512;
      f32x4 fac[8];
      #pragma unroll
      for (int nt=0;nt<8;nt++) fac[nt]=(f32x4){0.f,0.f,0.f,0.f};
      for (int c0i=0;c0i<4;c0i++){
        // FF1: wave w computes feature tile c0i*8+w -> chA cols w*16..
        { int n=(c0i*8+wid)*16+l15;
          bf16x8 b1[4];
          #pragma unroll
          for (int kk=0;kk<4;kk++)
            b1[kk]=*(const bf16x8*)(w1l + (size_t)n*H + kk*32 + l4*8);
          float bias1=ff1_b[ll*512+n];
          for (int mt=0;mt<8;mt++){
            f32x4 c={0.f,0.f,0.f,0.f};
            #pragma unroll
            for (int kk=0;kk<4;kk++){
              bf16x8 a=*(const bf16x8*)(hlb + (mt*16+l15)*S1 + kk*32 + l4*8);
              c=__builtin_amdgcn_mfma_f32_16x16x32_bf16(a,b1[kk],c,0,0,0);
            }
            int rb=mt*16+l4*4;
            #pragma unroll
            for (int reg=0;reg<4;reg++)
              chA[(rb+reg)*S1 + wid*16+l15]=f2b(fmaxf(c[reg]+bias1,0.f));
          }
        }
        __syncthreads();
        // FF2 partial: A = chA own stripe; B = Wff2 slice from global (L2)
        { bf16x8 a2[4];
          #pragma unroll
          for (int kk=0;kk<4;kk++)
            a2[kk]=*(const bf16x8*)(chA + (wid*16+l15)*S1 + kk*32 + l4*8);
          #pragma unroll
          for (int nt=0;nt<8;nt++){
            int n2=nt*16+l15;
            #pragma unroll
            for (int kk=0;kk<4;kk++){
              bf16x8 bb=*(const bf16x8*)(w2l + (size_t)n2*512 + c0i*128 + kk*32 + l4*8);
              fac[nt]=__builtin_amdgcn_mfma_f32_16x16x32_bf16(a2[kk],bb,fac[nt],0,0,0);
            }
          }
        }
        __syncthreads();
      }
      #pragma unroll
      for (int nt=0;nt<8;nt++){
        float b2v=ff2_b[ll*H + nt*16+l15];
        #pragma unroll
        for (int reg=0;reg<4;reg++) tokacc[nt][reg]+=fac[nt][reg]+b2v;
      }
    }
  }

  // ---- final LN on token-0 rows, compact to hlb rows 0..31
  { float s=0.f,q=0.f;
    #pragma unroll
    for (int nt=0;nt<8;nt++){ float v=tokacc[nt][0]; s+=v; q+=v*v; }
    #pragma unroll
    for (int m=1;m<16;m<<=1){ s+=__shfl_xor(s,m); q+=__shfl_xor(q,m); }
    float mean=s*(1.f/128.f);
    float rs=rsqrtf(q*(1.f/128.f)-mean*mean+1e-5f);
    int ci=wid*4+l4;
    #pragma unroll
    for (int nt=0;nt<8;nt++){
      int col=nt*16+l15;
      float hv=(tokacc[nt][0]-mean)*rs*fin_g[col]+fin_b[col];
      hlb[ci*S1+col]=f2b(hv);
    }
  }
  __syncthreads();

  // ---- head GEMM1 [32x128]@hw1^T + gelu
  float gel[2][4];
  { int n=wid*16+l15;
    bf16x8 bh[4];
    #pragma unroll
    for (int kk=0;kk<4;kk++)
      bh[kk]=*(const bf16x8*)(hw1b + (size_t)n*H + kk*32 + l4*8);
    float hb1v=hb1[n];
    #pragma unroll
    for (int mt=0;mt<2;mt++){
      f32x4 c={0.f,0.f,0.f,0.f};
      #pragma unroll
      for (int kk=0;kk<4;kk++){
        bf16x8 a=*(const bf16x8*)(hlb + (mt*16+l15)*S1 + kk*32 + l4*8);
        c=__builtin_amdgcn_mfma_f32_16x16x32_bf16(a,bh[kk],c,0,0,0);
      }
      #pragma unroll
      for (int reg=0;reg<4;reg++){
        float xx=c[reg]+hb1v;
        gel[mt][reg]=0.5f*xx*(1.f+erff(xx*0.70710678118654752f));
      }
    }
  }
  // ---- head LN (cross-wave)
  #pragma unroll
  for (int mt=0;mt<2;mt++){
    #pragma unroll
    for (int reg=0;reg<4;reg++){
      float v=gel[mt][reg], sv=v, qv=v*v;
      #pragma unroll
      for (int m=1;m<16;m<<=1){ sv+=__shfl_xor(sv,m); qv+=__shfl_xor(qv,m); }
      if (l15==0){ int r32=mt*16+l4*4+reg; red_s[r32*8+wid]=sv; red_q[r32*8+wid]=qv; }
    }
  }
  __syncthreads();
  if (tid<32){
    float ss=0.f,qs=0.f;
    #pragma unroll
    for (int w=0;w<8;w++){ ss+=red_s[tid*8+w]; qs+=red_q[tid*8+w]; }
    float mm=ss*(1.f/128.f);
    stat_m[tid]=mm;
    stat_r[tid]=rsqrtf(qs*(1.f/128.f)-mm*mm+1e-5f);
  }
  __syncthreads();
  { int n=wid*16+l15;
    float hg=hlng[n], hbv=hlnb[n];
    #pragma unroll
    for (int mt=0;mt<2;mt++){
      #pragma unroll
      for (int reg=0;reg<4;reg++){
        int r32=mt*16+l4*4+reg;
        float z=(gel[mt][reg]-stat_m[r32])*stat_r[r32]*hg+hbv;
        hlb[r32*S1+n]=f2b(z);
      }
    }
  }
  __syncthreads();

  // ---- head GEMM2 [32x128] @ hw2^T -> out (waves 0,1)
  if (wid<2){
    int mt=wid;
    bool valid=l15<10;
    bf16x8 b2[4];
    #pragma unroll
    for (int kk=0;kk<4;kk++){
      if (valid) b2[kk]=*(const bf16x8*)(hw2b + (size_t)l15*H + kk*32 + l4*8);
      else { bf16x8 z; for (int t=0;t<8;t++) z[t]=0; b2[kk]=z; }
    }
    f32x4 c={0.f,0.f,0.f,0.f};
    #pragma unroll
    for (int kk=0;kk<4;kk++){
      bf16x8 a=*(const bf16x8*)(hlb + (mt*16+l15)*S1 + kk*32 + l4*8);
      c=__builtin_amdgcn_mfma_f32_16x16x32_bf16(a,b2[kk],c,0,0,0);
    }
    if (valid){
      float bb2=hb2[l15];
      #pragma unroll
      for (int reg=0;reg<4;reg++){
        int i=mt*16+l4*4+reg;
        out[((size_t)node0+i)*10 + l15]=c[reg]+bb2;
      }
    }
  }
}

extern "C" void kernel_launch(void* const* d_in, const int* in_sizes, int n_in,
                              void* d_out, int out_size, void* d_ws, size_t ws_size,
                              hipStream_t stream){
  const float* x       =(const float*)d_in[0];
  const int*   ei      =(const int*)  d_in[1];
  const float* eigvecs =(const float*)d_in[2];
  const float* eigvals =(const float*)d_in[3];
  const float* enc_w   =(const float*)d_in[4];
  const float* enc_b   =(const float*)d_in[5];
  const float* in_ln_g =(const float*)d_in[6];
  const float* in_ln_b =(const float*)d_in[7];
  const float* pe_phi_w1=(const float*)d_in[8];
  const float* pe_phi_w2=(const float*)d_in[9];
  const float* pe_rho_w1=(const float*)d_in[10];
  const float* pe_rho_b1=(const float*)d_in[11];
  const float* pe_rho_w2=(const float*)d_in[12];
  const float* pe_rho_b2=(const float*)d_in[13];
  const float* pe_eps  =(const float*)d_in[14];
  const float* hop_emb =(const float*)d_in[15];
  const float* qkv_w   =(const float*)d_in[16];
  const float* qkv_b   =(const float*)d_in[17];
  const float* out_w   =(const float*)d_in[18];
  const float* out_b   =(const float*)d_in[19];
  const float* ln1_g   =(const float*)d_in[20];
  const float* ln1_b   =(const float*)d_in[21];
  const float* ln2_g   =(const float*)d_in[22];
  const float* ln2_b   =(const float*)d_in[23];
  const float* ff1_w   =(const float*)d_in[24];
  const float* ff1_b   =(const float*)d_in[25];
  const float* ff2_w   =(const float*)d_in[26];
  const float* ff2_b   =(const float*)d_in[27];
  const float* fin_g   =(const float*)d_in[28];
  const float* fin_b   =(const float*)d_in[29];
  const float* hw1     =(const float*)d_in[30];
  const float* hb1     =(const float*)d_in[31];
  const float* hlg     =(const float*)d_in[32];
  const float* hlb_    =(const float*)d_in[33];
  const float* hw2     =(const float*)d_in[34];
  const float* hb2     =(const float*)d_in[35];

  char* ws=(char*)d_ws;
  size_t off=0;
  auto alloc=[&](size_t bytes)->void*{
    void* p=ws+off;
    off+=(bytes+255)&~(size_t)255;
    return p;
  };
  float* tokens =(float*)alloc((size_t)NN*4*H*sizeof(float));   // 204.8 MB
  float* deg    =(float*)alloc((size_t)NN*sizeof(float));       // becomes dinv
  int*   counts =(int*)  alloc((size_t)NN*sizeof(int));
  int*   row_ptr=(int*)  alloc((size_t)(NN+1)*sizeof(int));
  int*   cursor =(int*)  alloc((size_t)NN*sizeof(int));
  int*   cs_col =(int*)  alloc((size_t)EE*sizeof(int));
  float* cs_w   =(float*)alloc((size_t)EE*sizeof(float));
  int*   flag   =(int*)  alloc(256);
  // bf16 weight copies
  ushort* wqkvb =(ushort*)alloc((size_t)2*384*H*sizeof(ushort));
  ushort* woutb =(ushort*)alloc((size_t)2*H*H*sizeof(ushort));
  ushort* wff1b =(ushort*)alloc((size_t)2*512*H*sizeof(ushort));
  ushort* wff2b =(ushort*)alloc((size_t)2*H*512*sizeof(ushort));
  ushort* hw1b  =(ushort*)alloc((size_t)H*H*sizeof(ushort));
  ushort* hw2b  =(ushort*)alloc((size_t)10*H*sizeof(ushort));
  ushort* wpw2b =(ushort*)alloc((size_t)H*H*sizeof(ushort));
  ushort* wrw1b =(ushort*)alloc((size_t)H*H*sizeof(ushort));
  ushort* wrw2b =(ushort*)alloc((size_t)H*H*sizeof(ushort));
  ushort* wencb =(ushort*)alloc((size_t)H*H*sizeof(ushort));
  if (off>ws_size) return; // workspace insufficient

  hipMemsetAsync(deg,0,(size_t)NN*sizeof(float),stream);
  hipMemsetAsync(counts,0,(size_t)NN*sizeof(int),stream);
  detect_kernel<<<1,256,0,stream>>>(ei,flag);
  // weight conversions
  cvtw_kernel<<<(2*384*H+255)/256,256,0,stream>>>(qkv_w,wqkvb,2*384*H);
  cvtw_kernel<<<(2*H*H+255)/256,256,0,stream>>>(out_w,woutb,2*H*H);
  cvtw_kernel<<<(2*512*H+255)/256,256,0,stream>>>(ff1_w,wff1b,2*512*H);
  cvtw_kernel<<<(2*H*512+255)/256,256,0,stream>>>(ff2_w,wff2b,2*H*512);
  cvtw_kernel<<<(H*H+255)/256,256,0,stream>>>(hw1,hw1b,H*H);
  cvtw_kernel<<<(10*H+255)/256,256,0,stream>>>(hw2,hw2b,10*H);
  cvtw_kernel<<<(H*H+255)/256,256,0,stream>>>(pe_phi_w2,wpw2b,H*H);
  cvtw_kernel<<<(H*H+255)/256,256,0,stream>>>(pe_rho_w1,wrw1b,H*H);
  cvtw_kernel<<<(H*H+255)/256,256,0,stream>>>(pe_rho_w2,wrw2b,H*H);
  cvtw_kernel<<<(H*H+255)/256,256,0,stream>>>(enc_w,wencb,H*H);

  enc2_kernel<<<(NN+127)/128,512,0,stream>>>(x,wencb,enc_b,in_ln_g,in_ln_b,tokens);
  hist_kernel<<<(EE+255)/256,256,0,stream>>>(ei,flag,deg,counts);
  dinv_kernel<<<(NN+255)/256,256,0,stream>>>(deg);
  scan_kernel<<<1,1024,0,stream>>>(counts,row_ptr,cursor);
  scatter_kernel<<<(EE+255)/256,256,0,stream>>>(ei,flag,cursor,deg,cs_col,cs_w);
  for (int k=0;k<3;k++)
    spmm_kernel<<<NN/2,256,0,stream>>>(tokens,row_ptr,cs_col,cs_w,k);
  pe2_kernel<<<(NN+127)/128,512,0,stream>>>(eigvecs,eigvals,pe_phi_w1,pe_eps,
                                            wpw2b,wrw1b,pe_rho_b1,wrw2b,pe_rho_b2,
                                            tokens);
  xform3_kernel<<<NN/32,512,0,stream>>>(tokens,hop_emb,
                                        wqkvb,qkv_b,woutb,out_b,
                                        ln1_g,ln1_b,ln2_g,ln2_b,
                                        wff1b,ff1_b,wff2b,ff2_b,
                                        fin_g,fin_b,hw1b,hb1,hlg,hlb_,hw2b,hb2,
                                        (float*)d_out);
}